// Round 1
// 463.574 us; speedup vs baseline: 1.0731x; 1.0731x over previous
//
#include <hip/hip_runtime.h>
#include <math.h>

#define LEVELS 16
#define TBL 524288          // 2^19 entries per level
#define TMASK (TBL - 1)

typedef short bf16x8 __attribute__((ext_vector_type(8)));
typedef float f32x4  __attribute__((ext_vector_type(4)));

static __device__ __forceinline__ unsigned short f2bf(float x) {
    unsigned u = __float_as_uint(x);
    u += 0x7fffu + ((u >> 16) & 1u);    // RNE
    return (unsigned short)(u >> 16);
}
static __device__ __forceinline__ float b2f(unsigned short h) {
    return __uint_as_float(((unsigned)h) << 16);
}

// SH degree-4 block, constants computed exactly as round-1 (verified correct).
#define SH_BLOCK(sh, dx, dy, dz)                                                          \
    const float x2 = dx * dx, y2 = dy * dy, z2 = dz * dz;                                 \
    const float xy = dx * dy, xz = dx * dz, yz = dy * dz;                                 \
    const float x4 = x2 * x2, y4 = y2 * y2;                                               \
    const float c0  = (float)(0.5 * sqrt(1.0 / M_PI));                                    \
    const float c1  = (float)(0.5 * sqrt(3.0 / M_PI));                                    \
    const float sub = (float)(0.25 * sqrt(5.0 / M_PI));                                   \
    const float v1  = (float)(0.25 * sqrt(15.0 / M_PI));                                  \
    const float v2  = (float)(0.5 * sqrt(15.0 / M_PI));                                   \
    const float v3  = (float)(0.75 * sqrt(5.0 / M_PI));                                   \
    const float w1c = (float)(0.25 * sqrt(105.0 / M_PI));                                 \
    const float w2c = (float)(0.5 * sqrt(105.0 / M_PI));                                  \
    const float w3c = (float)(0.25 * sqrt(35.0 / (2.0 * M_PI)));                          \
    const float w4c = (float)(0.5 * sqrt(7.0 / (6.0 * M_PI)));                            \
    sh[0] = c0;                                                                           \
    sh[1] = -c1 * dy;                                                                     \
    sh[2] =  c1 * dz;                                                                     \
    sh[3] = -c1 * dx;                                                                     \
    sh[4] =  v2 * xy;                                                                     \
    sh[5] = -v2 * yz;                                                                     \
    sh[6] =  v3 * z2 - sub;                                                               \
    sh[7] = -v2 * xz;                                                                     \
    sh[8] =  v1 * x2 - v1 * y2;                                                           \
    sh[9]  = -w3c * dy * (3.0f * x2 - y2);                                                \
    sh[10] =  w2c * xy * dz;                                                              \
    sh[11] =  w4c * dy * (1.5f - 7.5f * z2);                                              \
    sh[12] =  1.24392110863372f * dz * (1.5f * z2 - 0.5f) - 0.497568443453487f * dz;      \
    sh[13] =  w4c * dx * (1.5f - 7.5f * z2);                                              \
    sh[14] =  w1c * dz * (x2 - y2);                                                       \
    sh[15] = -w3c * dx * (x2 - 3.0f * y2);                                                \
    sh[16] =  2.5033429417967f * xy * (x2 - y2);                                          \
    sh[17] = -1.77013076977993f * yz * (3.0f * x2 - y2);                                  \
    sh[18] =  0.126156626101008f * xy * (52.5f * z2 - 7.5f);                              \
    sh[19] =  0.267618617422916f * dy * (2.33333333333333f * dz * (1.5f - 7.5f * z2) + 4.0f * dz); \
    sh[20] =  1.48099765681286f * dz * (1.66666666666667f * dz * (1.5f * z2 - 0.5f) - 0.666666666666667f * dz) \
              - 0.952069922236839f * z2 + 0.317356640745613f;                             \
    sh[21] =  0.267618617422916f * dx * (2.33333333333333f * dz * (1.5f - 7.5f * z2) + 4.0f * dz); \
    sh[22] =  0.063078313050504f * (x2 - y2) * (52.5f * z2 - 7.5f);                       \
    sh[23] = -1.77013076977993f * xz * (x2 - 3.0f * y2);                                  \
    sh[24] = -3.75501441269506f * x2 * y2 + 0.625835735449176f * x4 + 0.625835735449176f * y4;

// ------------------------------------------------------------------
// Kernel 1: hash-grid gather with level<->XCD affinity.
// R11: output packed bf16 (2 features in one uint) via non-temporal
// store — bit-identical to the old f32-write + f2bf-on-read path,
// halves WRITE_SIZE and stops the write stream evicting table lines
// from L2 (FETCH_SIZE was 215 MB vs ~73 MB ideal).
// ------------------------------------------------------------------
__global__ __launch_bounds__(256)
void ngp_encode_lvl(const float* __restrict__ pos,
                    const float* __restrict__ tables,
                    unsigned int* __restrict__ wsp, int n)
{
    const int b = blockIdx.x;
    const int p = b & 7;
    const int h = b >> 14;                 // 16384 blocks per half (n = 2^19)
    const int l = 2 * p + h;
    const int c = (b & 16383) >> 3;
    const int idx = c * 256 + threadIdx.x;
    if (idx >= n || l >= LEVELS) return;

    const float px = pos[3 * idx + 0];
    const float py = pos[3 * idx + 1];
    const float pz = pos[3 * idx + 2];

    const float resf = (float)(16 << l);
    const float tx = px * resf, ty = py * resf, tz = pz * resf;
    const float fx = floorf(tx), fy = floorf(ty), fz = floorf(tz);
    const float wx = tx - fx, wy = ty - fy, wz = tz - fz;
    const unsigned ix = (unsigned)(int)fx;
    const unsigned iy = (unsigned)(int)fy;
    const unsigned iz = (unsigned)(int)fz;
    const unsigned hy0 = iy * 2654435761u, hy1 = hy0 + 2654435761u;
    const unsigned hz0 = iz * 805459861u,  hz1 = hz0 + 805459861u;
    const unsigned ix1 = ix + 1u;

    const float2* tb = (const float2*)tables + (size_t)l * TBL;
    const float2 e000 = tb[(ix  ^ hy0 ^ hz0) & TMASK];
    const float2 e001 = tb[(ix  ^ hy0 ^ hz1) & TMASK];
    const float2 e010 = tb[(ix  ^ hy1 ^ hz0) & TMASK];
    const float2 e011 = tb[(ix  ^ hy1 ^ hz1) & TMASK];
    const float2 e100 = tb[(ix1 ^ hy0 ^ hz0) & TMASK];
    const float2 e101 = tb[(ix1 ^ hy0 ^ hz1) & TMASK];
    const float2 e110 = tb[(ix1 ^ hy1 ^ hz0) & TMASK];
    const float2 e111 = tb[(ix1 ^ hy1 ^ hz1) & TMASK];

    const float ux = 1.f - wx, uy = 1.f - wy, uz = 1.f - wz;
    const float c000 = ux * uy * uz, c001 = ux * uy * wz;
    const float c010 = ux * wy * uz, c011 = ux * wy * wz;
    const float c100 = wx * uy * uz, c101 = wx * uy * wz;
    const float c110 = wx * wy * uz, c111 = wx * wy * wz;

    float f0 = e000.x * c000, f1 = e000.y * c000;
    f0 = fmaf(e001.x, c001, f0); f1 = fmaf(e001.y, c001, f1);
    f0 = fmaf(e010.x, c010, f0); f1 = fmaf(e010.y, c010, f1);
    f0 = fmaf(e011.x, c011, f0); f1 = fmaf(e011.y, c011, f1);
    f0 = fmaf(e100.x, c100, f0); f1 = fmaf(e100.y, c100, f1);
    f0 = fmaf(e101.x, c101, f0); f1 = fmaf(e101.y, c101, f1);
    f0 = fmaf(e110.x, c110, f0); f1 = fmaf(e110.y, c110, f1);
    f0 = fmaf(e111.x, c111, f0); f1 = fmaf(e111.y, c111, f1);

    const unsigned int h0 = f2bf(f0);
    const unsigned int h1 = f2bf(f1);
    __builtin_nontemporal_store((h1 << 16) | h0, &wsp[(size_t)l * n + idx]);
}

// ------------------------------------------------------------------
// Kernel 2: split-precision MFMA MLP, persistent blocks.
// R11: 512-thread blocks (8 waves) x 512 blocks -> 2 blocks/CU =
// 16 waves/CU = 4 waves/SIMD (was 2). The 47.9 KB weight stage is
// now amortized over twice the waves; act stride SA 66->65 keeps
// total LDS at 81,152 B/block (2 fit in 160 KiB) and improves read
// bank spread (4-way -> 2-way). ws2 reads are packed bf16 (no f2bf
// on the read path). sh[] stores fully unrolled + predicated so the
// array stays in registers (rule #20). Biases hoisted out of the
// group loop. Inner math identical to R8/R9 (absmax 3.9e-3).
// ------------------------------------------------------------------
#define MT   512
#define GROUPS 8
#define SW1  32                  // Wd1 k-stride (shorts), rows 16B-aligned
#define SW   72                  // 64-k weight stride (shorts), rows 16B-aligned
#define SA   65                  // act k-stride (floats)
#define OW1  0                   // 64*32 = 2048
#define OW2  2048                // 16*72 = 1152
#define OC1H 3200                // 64*72 = 4608
#define OC1L 7808
#define OC2H 12416
#define OC2L 17024
#define OC3H 21632               // 16*72 = 1152
#define OC3L 22784
#define WTOT 23936               // shorts = 47,872 B; + act 33,280 B = 81,152 B

__global__ __launch_bounds__(512, 4)
void ngp_mlp_mfma4(const unsigned int* __restrict__ wsp,
                   const float* __restrict__ dirp,
                   const float* __restrict__ Wd1, const float* __restrict__ bd1,
                   const float* __restrict__ Wd2, const float* __restrict__ bd2,
                   const float* __restrict__ Wc1, const float* __restrict__ bc1,
                   const float* __restrict__ Wc2, const float* __restrict__ bc2,
                   const float* __restrict__ Wc3, const float* __restrict__ bc3,
                   float* __restrict__ out, int n)
{
    __shared__ short wsm[WTOT];
    __shared__ float act[8 * 16 * SA];
    const int tid = threadIdx.x;

    for (int t = tid; t < WTOT; t += MT) wsm[t] = 0;
    __syncthreads();

    for (int g = tid; g < 32 * 64; g += MT) {            // Wd1 (32,64) single
        const int k = g >> 6, nn = g & 63;
        wsm[OW1 + nn * SW1 + k] = f2bf(Wd1[g]);
    }
    for (int g = tid; g < 64 * 16; g += MT) {            // Wd2 (64,16) single
        const int k = g >> 4, nn = g & 15;
        wsm[OW2 + nn * SW + k] = f2bf(Wd2[g]);
    }
    for (int g = tid; g < 41 * 64; g += MT) {            // Wc1 (41,64) hi+lo
        const int k = g >> 6, nn = g & 63;
        const float w = Wc1[g];
        const unsigned short hh = f2bf(w);
        wsm[OC1H + nn * SW + k] = hh;
        wsm[OC1L + nn * SW + k] = f2bf(w - b2f(hh));
    }
    for (int g = tid; g < 64 * 64; g += MT) {            // Wc2 (64,64) hi+lo
        const int k = g >> 6, nn = g & 63;
        const float w = Wc2[g];
        const unsigned short hh = f2bf(w);
        wsm[OC2H + nn * SW + k] = hh;
        wsm[OC2L + nn * SW + k] = f2bf(w - b2f(hh));
    }
    for (int g = tid; g < 64 * 3; g += MT) {             // Wc3 (64,3) hi+lo
        const int k = g / 3, nn = g - 3 * k;
        const float w = Wc3[g];
        const unsigned short hh = f2bf(w);
        wsm[OC3H + nn * SW + k] = hh;
        wsm[OC3L + nn * SW + k] = f2bf(w - b2f(hh));
    }
    __syncthreads();

    const int wid = tid >> 6;              // 0..7
    const int lane = tid & 63;
    const int ln = lane & 15;
    const int qd = lane >> 4;
    float* A = act + wid * (16 * SA);

    // biases hoisted to registers (loop-invariant)
    float bd1v[4], bc1v[4], bc2v[4];
#pragma unroll
    for (int t = 0; t < 4; ++t) {
        bd1v[t] = bd1[t * 16 + ln];
        bc1v[t] = bc1[t * 16 + ln];
        bc2v[t] = bc2[t * 16 + ln];
    }
    const float bd2v = bd2[ln];
    const float bc3v = (ln < 3) ? bc3[ln] : 0.f;

#define LOAD_SPLIT(ah, al, k0)                                   \
    {                                                            \
        _Pragma("unroll")                                        \
        for (int j = 0; j < 8; ++j) {                            \
            const float v = A[ln * SA + (k0) + j];               \
            const unsigned short hb = f2bf(v);                   \
            ah[j] = (short)hb;                                   \
            al[j] = (short)f2bf(v - b2f(hb));                    \
        }                                                        \
    }

#define SPLIT_TILE(acc, ah0, ah1, al0, al1, OH, OL, row)                                          \
    {                                                                                             \
        const bf16x8 bh0 = *(const bf16x8*)&wsm[(OH) + (row) * SW + qd * 8];                      \
        const bf16x8 bh1 = *(const bf16x8*)&wsm[(OH) + (row) * SW + 32 + qd * 8];                 \
        const bf16x8 bl0 = *(const bf16x8*)&wsm[(OL) + (row) * SW + qd * 8];                      \
        const bf16x8 bl1 = *(const bf16x8*)&wsm[(OL) + (row) * SW + 32 + qd * 8];                 \
        acc = __builtin_amdgcn_mfma_f32_16x16x32_bf16(ah0, bh0, acc, 0, 0, 0);                    \
        acc = __builtin_amdgcn_mfma_f32_16x16x32_bf16(ah1, bh1, acc, 0, 0, 0);                    \
        acc = __builtin_amdgcn_mfma_f32_16x16x32_bf16(al0, bh0, acc, 0, 0, 0);                    \
        acc = __builtin_amdgcn_mfma_f32_16x16x32_bf16(al1, bh1, acc, 0, 0, 0);                    \
        acc = __builtin_amdgcn_mfma_f32_16x16x32_bf16(ah0, bl0, acc, 0, 0, 0);                    \
        acc = __builtin_amdgcn_mfma_f32_16x16x32_bf16(ah1, bl1, acc, 0, 0, 0);                    \
    }

    // ---- register prefetch of group 0's globals (packed bf16 planes) ----
    const int pt0 = blockIdx.x * (GROUPS * 128) + wid * 16 + ln;
    unsigned int xu0, xu1, xu2, xu3;
    float dq0, dq1, dq2;
    xu0 = wsp[(size_t)(qd * 4 + 0) * n + pt0];
    xu1 = wsp[(size_t)(qd * 4 + 1) * n + pt0];
    xu2 = wsp[(size_t)(qd * 4 + 2) * n + pt0];
    xu3 = wsp[(size_t)(qd * 4 + 3) * n + pt0];
    dq0 = dirp[3 * pt0 + 0];
    dq1 = dirp[3 * pt0 + 1];
    dq2 = dirp[3 * pt0 + 2];

#pragma unroll 1
    for (int grp = 0; grp < GROUPS; ++grp) {
        const int pt_base = blockIdx.x * (GROUPS * 128) + grp * 128 + wid * 16;
        const int pt = pt_base + ln;

        // consume prefetched globals (already bf16 bits — no converts)
        bf16x8 ax;
        ax[0] = (short)(xu0 & 0xffffu); ax[1] = (short)(xu0 >> 16);
        ax[2] = (short)(xu1 & 0xffffu); ax[3] = (short)(xu1 >> 16);
        ax[4] = (short)(xu2 & 0xffffu); ax[5] = (short)(xu2 >> 16);
        ax[6] = (short)(xu3 & 0xffffu); ax[7] = (short)(xu3 >> 16);
        const float ddx = dq0, ddy = dq1, ddz = dq2;

        // issue next group's globals now (consumed next iteration)
        if (grp + 1 < GROUPS) {
            const int ptn = pt + 128;
            xu0 = wsp[(size_t)(qd * 4 + 0) * n + ptn];
            xu1 = wsp[(size_t)(qd * 4 + 1) * n + ptn];
            xu2 = wsp[(size_t)(qd * 4 + 2) * n + ptn];
            xu3 = wsp[(size_t)(qd * 4 + 3) * n + ptn];
            dq0 = dirp[3 * ptn + 0];
            dq1 = dirp[3 * ptn + 1];
            dq2 = dirp[3 * ptn + 2];
        }

        // ---- d1: Y[16x64] = X @ Wd1 (single bf16) ----
        f32x4 yacc[4];
#pragma unroll
        for (int t = 0; t < 4; ++t) {
            const bf16x8 b = *(const bf16x8*)&wsm[OW1 + (t * 16 + ln) * SW1 + qd * 8];
            const float bv = bd1v[t];
            f32x4 acc = {bv, bv, bv, bv};
            yacc[t] = __builtin_amdgcn_mfma_f32_16x16x32_bf16(ax, b, acc, 0, 0, 0);
        }
#pragma unroll
        for (int t = 0; t < 4; ++t)
#pragma unroll
            for (int r = 0; r < 4; ++r)
                A[(qd * 4 + r) * SA + t * 16 + ln] = fmaxf(yacc[t][r], 0.f);   // fp32

        // ---- d2: D[16x16] = relu(Y) @ Wd2 (single bf16) ----
        {
            bf16x8 a0, a1;
#pragma unroll
            for (int j = 0; j < 8; ++j) a0[j] = (short)f2bf(A[ln * SA + qd * 8 + j]);
#pragma unroll
            for (int j = 0; j < 8; ++j) a1[j] = (short)f2bf(A[ln * SA + 32 + qd * 8 + j]);
            const bf16x8 b0 = *(const bf16x8*)&wsm[OW2 + ln * SW + qd * 8];
            const bf16x8 b1 = *(const bf16x8*)&wsm[OW2 + ln * SW + 32 + qd * 8];
            const float bv = bd2v;
            f32x4 acc = {bv, bv, bv, bv};
            acc = __builtin_amdgcn_mfma_f32_16x16x32_bf16(a0, b0, acc, 0, 0, 0);
            acc = __builtin_amdgcn_mfma_f32_16x16x32_bf16(a1, b1, acc, 0, 0, 0);
            if (ln == 15) {
#pragma unroll
                for (int r = 0; r < 4; ++r)
                    out[3 * n + pt_base + qd * 4 + r] = fmaxf(acc[r], 0.f);    // sigma
            }
#pragma unroll
            for (int r = 0; r < 4; ++r)
                A[(qd * 4 + r) * SA + ln] = acc[r];        // raw D fp32, k=0..15
        }

        // ---- SH -> act fp32, k=16..40 (k=41..63 stale, Wc1 rows zeroed) ----
        // Fully unrolled + predicated: sh[] static-indexed -> stays in VGPRs.
        {
            float sh[25];
            SH_BLOCK(sh, ddx, ddy, ddz)
#pragma unroll
            for (int i = 0; i < 25; ++i)
                if ((i & 3) == qd)
                    A[ln * SA + 16 + i] = sh[i];
        }

        // ---- c1: H1 = [D|SH|0] @ Wc1 (split) ----
        {
            bf16x8 ah0, ah1, al0, al1;
            LOAD_SPLIT(ah0, al0, qd * 8)
            LOAD_SPLIT(ah1, al1, 32 + qd * 8)
            f32x4 hacc[4];
#pragma unroll
            for (int t = 0; t < 4; ++t) {
                const float bv = bc1v[t];
                f32x4 acc = {bv, bv, bv, bv};
                SPLIT_TILE(acc, ah0, ah1, al0, al1, OC1H, OC1L, t * 16 + ln)
                hacc[t] = acc;
            }
#pragma unroll
            for (int t = 0; t < 4; ++t)
#pragma unroll
                for (int r = 0; r < 4; ++r)
                    A[(qd * 4 + r) * SA + t * 16 + ln] = fmaxf(hacc[t][r], 0.f);
        }

        // ---- c2: H2 = relu(H1) @ Wc2 (split) ----
        {
            bf16x8 ah0, ah1, al0, al1;
            LOAD_SPLIT(ah0, al0, qd * 8)
            LOAD_SPLIT(ah1, al1, 32 + qd * 8)
            f32x4 hacc[4];
#pragma unroll
            for (int t = 0; t < 4; ++t) {
                const float bv = bc2v[t];
                f32x4 acc = {bv, bv, bv, bv};
                SPLIT_TILE(acc, ah0, ah1, al0, al1, OC2H, OC2L, t * 16 + ln)
                hacc[t] = acc;
            }
#pragma unroll
            for (int t = 0; t < 4; ++t)
#pragma unroll
                for (int r = 0; r < 4; ++r)
                    A[(qd * 4 + r) * SA + t * 16 + ln] = fmaxf(hacc[t][r], 0.f);
        }

        // ---- c3 + sigmoid: R = relu(H2) @ Wc3 (split) ----
        {
            bf16x8 ah0, ah1, al0, al1;
            LOAD_SPLIT(ah0, al0, qd * 8)
            LOAD_SPLIT(ah1, al1, 32 + qd * 8)
            const float bv = bc3v;
            f32x4 acc = {bv, bv, bv, bv};
            SPLIT_TILE(acc, ah0, ah1, al0, al1, OC3H, OC3L, ln)
            if (ln < 3) {
#pragma unroll
                for (int r = 0; r < 4; ++r)
                    out[3 * (pt_base + qd * 4 + r) + ln] = 1.f / (1.f + expf(-acc[r]));
            }
        }
    }
}

// ------------------------------------------------------------------
// Fallback: round-1 fused kernel (if ws too small / n not 2^19) — proven
// ------------------------------------------------------------------
__global__ __launch_bounds__(256)
void nerf_fused(const float* __restrict__ pos,
                const float* __restrict__ dirp,
                const float* __restrict__ tables,
                const float* __restrict__ Wd1, const float* __restrict__ bd1,
                const float* __restrict__ Wd2, const float* __restrict__ bd2,
                const float* __restrict__ Wc1, const float* __restrict__ bc1,
                const float* __restrict__ Wc2, const float* __restrict__ bc2,
                const float* __restrict__ Wc3, const float* __restrict__ bc3,
                float* __restrict__ out, int n)
{
    const int idx = blockIdx.x * blockDim.x + threadIdx.x;
    if (idx >= n) return;
    const float px = pos[3 * idx + 0], py = pos[3 * idx + 1], pz = pos[3 * idx + 2];
    float y[64];
#pragma unroll
    for (int j = 0; j < 64; ++j) y[j] = bd1[j];
#pragma unroll
    for (int l = 0; l < LEVELS; ++l) {
        const float resf = (float)(16 << l);
        const float tx = px * resf, ty = py * resf, tz = pz * resf;
        const float fx = floorf(tx), fy = floorf(ty), fz = floorf(tz);
        const float wx = tx - fx, wy = ty - fy, wz = tz - fz;
        const unsigned ix = (unsigned)(int)fx, iy = (unsigned)(int)fy, iz = (unsigned)(int)fz;
        const unsigned hy0 = iy * 2654435761u, hy1 = hy0 + 2654435761u;
        const unsigned hz0 = iz * 805459861u,  hz1 = hz0 + 805459861u;
        const unsigned ix1 = ix + 1u;
        const float2* tb = (const float2*)tables + (size_t)l * TBL;
        const float2 e000 = tb[(ix  ^ hy0 ^ hz0) & TMASK];
        const float2 e001 = tb[(ix  ^ hy0 ^ hz1) & TMASK];
        const float2 e010 = tb[(ix  ^ hy1 ^ hz0) & TMASK];
        const float2 e011 = tb[(ix  ^ hy1 ^ hz1) & TMASK];
        const float2 e100 = tb[(ix1 ^ hy0 ^ hz0) & TMASK];
        const float2 e101 = tb[(ix1 ^ hy0 ^ hz1) & TMASK];
        const float2 e110 = tb[(ix1 ^ hy1 ^ hz0) & TMASK];
        const float2 e111 = tb[(ix1 ^ hy1 ^ hz1) & TMASK];
        const float ux = 1.f - wx, uy = 1.f - wy, uz = 1.f - wz;
        const float c000 = ux*uy*uz, c001 = ux*uy*wz, c010 = ux*wy*uz, c011 = ux*wy*wz;
        const float c100 = wx*uy*uz, c101 = wx*uy*wz, c110 = wx*wy*uz, c111 = wx*wy*wz;
        float f0 = e000.x*c000, f1 = e000.y*c000;
        f0 = fmaf(e001.x,c001,f0); f1 = fmaf(e001.y,c001,f1);
        f0 = fmaf(e010.x,c010,f0); f1 = fmaf(e010.y,c010,f1);
        f0 = fmaf(e011.x,c011,f0); f1 = fmaf(e011.y,c011,f1);
        f0 = fmaf(e100.x,c100,f0); f1 = fmaf(e100.y,c100,f1);
        f0 = fmaf(e101.x,c101,f0); f1 = fmaf(e101.y,c101,f1);
        f0 = fmaf(e110.x,c110,f0); f1 = fmaf(e110.y,c110,f1);
        f0 = fmaf(e111.x,c111,f0); f1 = fmaf(e111.y,c111,f1);
        const float* w0 = Wd1 + (size_t)(2 * l) * 64;
#pragma unroll
        for (int j = 0; j < 64; ++j)
            y[j] = fmaf(f0, w0[j], fmaf(f1, w0[64 + j], y[j]));
    }
    float d[16];
#pragma unroll
    for (int k = 0; k < 16; ++k) d[k] = bd2[k];
#pragma unroll
    for (int j = 0; j < 64; ++j) {
        const float a = fmaxf(y[j], 0.f);
#pragma unroll
        for (int k = 0; k < 16; ++k) d[k] = fmaf(a, Wd2[j * 16 + k], d[k]);
    }
    out[3 * n + idx] = fmaxf(d[15], 0.f);
    const float dx = dirp[3*idx], dy = dirp[3*idx+1], dz = dirp[3*idx+2];
    float sh[25];
    SH_BLOCK(sh, dx, dy, dz)
    float h1[64];
#pragma unroll
    for (int j = 0; j < 64; ++j) h1[j] = bc1[j];
#pragma unroll
    for (int i = 0; i < 16; ++i) {
#pragma unroll
        for (int j = 0; j < 64; ++j) h1[j] = fmaf(d[i], Wc1[i * 64 + j], h1[j]);
    }
#pragma unroll
    for (int s = 0; s < 25; ++s) {
#pragma unroll
        for (int j = 0; j < 64; ++j) h1[j] = fmaf(sh[s], Wc1[(16 + s) * 64 + j], h1[j]);
    }
    float h2[64];
#pragma unroll
    for (int j = 0; j < 64; ++j) h2[j] = bc2[j];
#pragma unroll
    for (int i = 0; i < 64; ++i) {
        const float a = fmaxf(h1[i], 0.f);
#pragma unroll
        for (int j = 0; j < 64; ++j) h2[j] = fmaf(a, Wc2[i * 64 + j], h2[j]);
    }
    float r0 = bc3[0], r1 = bc3[1], r2 = bc3[2];
#pragma unroll
    for (int j = 0; j < 64; ++j) {
        const float a = fmaxf(h2[j], 0.f);
        r0 = fmaf(a, Wc3[j * 3 + 0], r0);
        r1 = fmaf(a, Wc3[j * 3 + 1], r1);
        r2 = fmaf(a, Wc3[j * 3 + 2], r2);
    }
    out[3 * idx + 0] = 1.f / (1.f + expf(-r0));
    out[3 * idx + 1] = 1.f / (1.f + expf(-r1));
    out[3 * idx + 2] = 1.f / (1.f + expf(-r2));
}

extern "C" void kernel_launch(void* const* d_in, const int* in_sizes, int n_in,
                              void* d_out, int out_size, void* d_ws, size_t ws_size,
                              hipStream_t stream) {
    const float* pos    = (const float*)d_in[0];
    const float* dir    = (const float*)d_in[1];
    const float* tables = (const float*)d_in[2];
    const float* Wd1 = (const float*)d_in[3];
    const float* bd1 = (const float*)d_in[4];
    const float* Wd2 = (const float*)d_in[5];
    const float* bd2 = (const float*)d_in[6];
    const float* Wc1 = (const float*)d_in[7];
    const float* bc1 = (const float*)d_in[8];
    const float* Wc2 = (const float*)d_in[9];
    const float* bc2 = (const float*)d_in[10];
    const float* Wc3 = (const float*)d_in[11];
    const float* bc3 = (const float*)d_in[12];

    const int n = in_sizes[0] / 3;
    const int blocks = (n + 255) / 256;
    const size_t need = (size_t)n * 64;    // 16 packed-bf16 planes = 4 B/point each

    if (ws_size >= need && n == 524288) {
        ngp_encode_lvl<<<16 * blocks, 256, 0, stream>>>(pos, tables, (unsigned int*)d_ws, n);
        ngp_mlp_mfma4<<<n / (128 * GROUPS), MT, 0, stream>>>((const unsigned int*)d_ws, dir,
                                                             Wd1, bd1, Wd2, bd2,
                                                             Wc1, bc1, Wc2, bc2, Wc3, bc3,
                                                             (float*)d_out, n);
    } else {
        nerf_fused<<<blocks, 256, 0, stream>>>(pos, dir, tables,
                                               Wd1, bd1, Wd2, bd2,
                                               Wc1, bc1, Wc2, bc2, Wc3, bc3,
                                               (float*)d_out, n);
    }
}

// Round 3
// 360.790 us; speedup vs baseline: 1.3788x; 1.2849x over previous
//
#include <hip/hip_runtime.h>
#include <math.h>

#define LEVELS 16
#define TBL 524288          // 2^19 entries per level
#define TMASK (TBL - 1)

typedef short bf16x8 __attribute__((ext_vector_type(8)));
typedef float f32x4  __attribute__((ext_vector_type(4)));
typedef float fvec4  __attribute__((ext_vector_type(4)));
typedef unsigned int uvec4 __attribute__((ext_vector_type(4)));

static __device__ __forceinline__ unsigned short f2bf(float x) {
    unsigned u = __float_as_uint(x);
    u += 0x7fffu + ((u >> 16) & 1u);    // RNE
    return (unsigned short)(u >> 16);
}
static __device__ __forceinline__ float b2f(unsigned short h) {
    return __uint_as_float(((unsigned)h) << 16);
}

// SH degree-4 block, constants computed exactly as round-1 (verified correct).
#define SH_BLOCK(sh, dx, dy, dz)                                                          \
    const float x2 = dx * dx, y2 = dy * dy, z2 = dz * dz;                                 \
    const float xy = dx * dy, xz = dx * dz, yz = dy * dz;                                 \
    const float x4 = x2 * x2, y4 = y2 * y2;                                               \
    const float c0  = (float)(0.5 * sqrt(1.0 / M_PI));                                    \
    const float c1  = (float)(0.5 * sqrt(3.0 / M_PI));                                    \
    const float sub = (float)(0.25 * sqrt(5.0 / M_PI));                                   \
    const float v1  = (float)(0.25 * sqrt(15.0 / M_PI));                                  \
    const float v2  = (float)(0.5 * sqrt(15.0 / M_PI));                                   \
    const float v3  = (float)(0.75 * sqrt(5.0 / M_PI));                                   \
    const float w1c = (float)(0.25 * sqrt(105.0 / M_PI));                                 \
    const float w2c = (float)(0.5 * sqrt(105.0 / M_PI));                                  \
    const float w3c = (float)(0.25 * sqrt(35.0 / (2.0 * M_PI)));                          \
    const float w4c = (float)(0.5 * sqrt(7.0 / (6.0 * M_PI)));                            \
    sh[0] = c0;                                                                           \
    sh[1] = -c1 * dy;                                                                     \
    sh[2] =  c1 * dz;                                                                     \
    sh[3] = -c1 * dx;                                                                     \
    sh[4] =  v2 * xy;                                                                     \
    sh[5] = -v2 * yz;                                                                     \
    sh[6] =  v3 * z2 - sub;                                                               \
    sh[7] = -v2 * xz;                                                                     \
    sh[8] =  v1 * x2 - v1 * y2;                                                           \
    sh[9]  = -w3c * dy * (3.0f * x2 - y2);                                                \
    sh[10] =  w2c * xy * dz;                                                              \
    sh[11] =  w4c * dy * (1.5f - 7.5f * z2);                                              \
    sh[12] =  1.24392110863372f * dz * (1.5f * z2 - 0.5f) - 0.497568443453487f * dz;      \
    sh[13] =  w4c * dx * (1.5f - 7.5f * z2);                                              \
    sh[14] =  w1c * dz * (x2 - y2);                                                       \
    sh[15] = -w3c * dx * (x2 - 3.0f * y2);                                                \
    sh[16] =  2.5033429417967f * xy * (x2 - y2);                                          \
    sh[17] = -1.77013076977993f * yz * (3.0f * x2 - y2);                                  \
    sh[18] =  0.126156626101008f * xy * (52.5f * z2 - 7.5f);                              \
    sh[19] =  0.267618617422916f * dy * (2.33333333333333f * dz * (1.5f - 7.5f * z2) + 4.0f * dz); \
    sh[20] =  1.48099765681286f * dz * (1.66666666666667f * dz * (1.5f * z2 - 0.5f) - 0.666666666666667f * dz) \
              - 0.952069922236839f * z2 + 0.317356640745613f;                             \
    sh[21] =  0.267618617422916f * dx * (2.33333333333333f * dz * (1.5f - 7.5f * z2) + 4.0f * dz); \
    sh[22] =  0.063078313050504f * (x2 - y2) * (52.5f * z2 - 7.5f);                       \
    sh[23] = -1.77013076977993f * xz * (x2 - 3.0f * y2);                                  \
    sh[24] = -3.75501441269506f * x2 * y2 + 0.625835735449176f * x4 + 0.625835735449176f * y4;

// ------------------------------------------------------------------
// Kernel 0 (R13): pack fp32 tables -> bf16x2 (one uint per entry).
// Halves the gather working set: the two levels affine to each XCD
// now total exactly 4 MB = one XCD L2. ~100 MB streamed, ~17 us.
// (ext_vector types: __builtin_nontemporal_* rejects HIP_vector_type.)
// ------------------------------------------------------------------
__global__ __launch_bounds__(256)
void cvt_tables(const float* __restrict__ tables,
                unsigned int* __restrict__ tb16, int total)
{
    const int i = (blockIdx.x * 256 + threadIdx.x) * 4;   // 4 entries/thread
    if (i >= total) return;
    const fvec4 a = __builtin_nontemporal_load((const fvec4*)(tables + 2 * (size_t)i));
    const fvec4 b = __builtin_nontemporal_load((const fvec4*)(tables + 2 * (size_t)i) + 1);
    uvec4 o;
    o.x = ((unsigned)f2bf(a.y) << 16) | f2bf(a.x);
    o.y = ((unsigned)f2bf(a.w) << 16) | f2bf(a.z);
    o.z = ((unsigned)f2bf(b.y) << 16) | f2bf(b.x);
    o.w = ((unsigned)f2bf(b.w) << 16) | f2bf(b.z);
    __builtin_nontemporal_store(o, (uvec4*)&tb16[i]);
}

// ------------------------------------------------------------------
// Kernel 1: hash-grid gather, level<->XCD affinity.
// R13: gathers hit the packed-bf16 table (4 B entries, halved working
// set), and the two x-corners of each (hy,hz) combo are merged into a
// single aligned 8 B load when ix is even (dim-0 prime is 1, so
// h(ix)^h(ix+1)==1 for even ix) -> avg 6 instead of 8 requests per
// point-level (-25% of the L2-request bottleneck).
// ------------------------------------------------------------------
__global__ __launch_bounds__(256)
void ngp_encode_lvl(const float* __restrict__ pos,
                    const unsigned int* __restrict__ tb16,
                    unsigned int* __restrict__ wsp, int n)
{
    const int b = blockIdx.x;
    const int p = b & 7;
    const int h = b >> 14;                 // 16384 blocks per half (n = 2^19)
    const int l = 2 * p + h;
    const int c = (b & 16383) >> 3;
    const int idx = c * 256 + threadIdx.x;
    if (idx >= n || l >= LEVELS) return;

    const float px = pos[3 * idx + 0];
    const float py = pos[3 * idx + 1];
    const float pz = pos[3 * idx + 2];

    const float resf = (float)(16 << l);
    const float tx = px * resf, ty = py * resf, tz = pz * resf;
    const float fx = floorf(tx), fy = floorf(ty), fz = floorf(tz);
    const float wx = tx - fx, wy = ty - fy, wz = tz - fz;
    const unsigned ix = (unsigned)(int)fx;
    const unsigned iy = (unsigned)(int)fy;
    const unsigned iz = (unsigned)(int)fz;
    const unsigned hy0 = iy * 2654435761u, hy1 = hy0 + 2654435761u;
    const unsigned hz0 = iz * 805459861u,  hz1 = hz0 + 805459861u;
    const unsigned ix1 = ix + 1u;

    const unsigned int* tb = tb16 + (size_t)l * TBL;
    const unsigned hA = hy0 ^ hz0;        // (y=0,z=0)
    const unsigned hB = hy0 ^ hz1;        // (y=0,z=1)
    const unsigned hC = hy1 ^ hz0;        // (y=1,z=0)
    const unsigned hD = hy1 ^ hz1;        // (y=1,z=1)

    unsigned eA0, eA1, eB0, eB1, eC0, eC1, eD0, eD1;   // e{combo}{x}
    if ((ix & 1u) == 0u) {
        // even ix: {ix^h, (ix+1)^h} = {m, m^1} -> one aligned 8B load
        const uint2 pA = *(const uint2*)&tb[((ix ^ hA) & TMASK) & ~1u];
        const uint2 pB = *(const uint2*)&tb[((ix ^ hB) & TMASK) & ~1u];
        const uint2 pC = *(const uint2*)&tb[((ix ^ hC) & TMASK) & ~1u];
        const uint2 pD = *(const uint2*)&tb[((ix ^ hD) & TMASK) & ~1u];
        const unsigned sA = hA & 1u, sB = hB & 1u, sC = hC & 1u, sD = hD & 1u;
        eA0 = sA ? pA.y : pA.x;  eA1 = sA ? pA.x : pA.y;
        eB0 = sB ? pB.y : pB.x;  eB1 = sB ? pB.x : pB.y;
        eC0 = sC ? pC.y : pC.x;  eC1 = sC ? pC.x : pC.y;
        eD0 = sD ? pD.y : pD.x;  eD1 = sD ? pD.x : pD.y;
    } else {
        eA0 = tb[(ix  ^ hA) & TMASK];  eA1 = tb[(ix1 ^ hA) & TMASK];
        eB0 = tb[(ix  ^ hB) & TMASK];  eB1 = tb[(ix1 ^ hB) & TMASK];
        eC0 = tb[(ix  ^ hC) & TMASK];  eC1 = tb[(ix1 ^ hC) & TMASK];
        eD0 = tb[(ix  ^ hD) & TMASK];  eD1 = tb[(ix1 ^ hD) & TMASK];
    }

#define UNPX(e) __uint_as_float((e) << 16)
#define UNPY(e) __uint_as_float((e) & 0xffff0000u)

    const float ux = 1.f - wx, uy = 1.f - wy, uz = 1.f - wz;
    const float c000 = ux * uy * uz, c001 = ux * uy * wz;
    const float c010 = ux * wy * uz, c011 = ux * wy * wz;
    const float c100 = wx * uy * uz, c101 = wx * uy * wz;
    const float c110 = wx * wy * uz, c111 = wx * wy * wz;

    float f0 = UNPX(eA0) * c000, f1 = UNPY(eA0) * c000;
    f0 = fmaf(UNPX(eB0), c001, f0); f1 = fmaf(UNPY(eB0), c001, f1);
    f0 = fmaf(UNPX(eC0), c010, f0); f1 = fmaf(UNPY(eC0), c010, f1);
    f0 = fmaf(UNPX(eD0), c011, f0); f1 = fmaf(UNPY(eD0), c011, f1);
    f0 = fmaf(UNPX(eA1), c100, f0); f1 = fmaf(UNPY(eA1), c100, f1);
    f0 = fmaf(UNPX(eB1), c101, f0); f1 = fmaf(UNPY(eB1), c101, f1);
    f0 = fmaf(UNPX(eC1), c110, f0); f1 = fmaf(UNPY(eC1), c110, f1);
    f0 = fmaf(UNPX(eD1), c111, f0); f1 = fmaf(UNPY(eD1), c111, f1);

    const unsigned int h0 = f2bf(f0);
    const unsigned int h1 = f2bf(f1);
    __builtin_nontemporal_store((h1 << 16) | h0, &wsp[(size_t)l * n + idx]);
}

// ------------------------------------------------------------------
// Kernel 2: split-precision MFMA MLP, persistent blocks (unchanged R11).
// ------------------------------------------------------------------
#define MT   512
#define GROUPS 8
#define SW1  32                  // Wd1 k-stride (shorts), rows 16B-aligned
#define SW   72                  // 64-k weight stride (shorts), rows 16B-aligned
#define SA   65                  // act k-stride (floats)
#define OW1  0                   // 64*32 = 2048
#define OW2  2048                // 16*72 = 1152
#define OC1H 3200                // 64*72 = 4608
#define OC1L 7808
#define OC2H 12416
#define OC2L 17024
#define OC3H 21632               // 16*72 = 1152
#define OC3L 22784
#define WTOT 23936               // shorts = 47,872 B; + act 33,280 B = 81,152 B

__global__ __launch_bounds__(512, 4)
void ngp_mlp_mfma4(const unsigned int* __restrict__ wsp,
                   const float* __restrict__ dirp,
                   const float* __restrict__ Wd1, const float* __restrict__ bd1,
                   const float* __restrict__ Wd2, const float* __restrict__ bd2,
                   const float* __restrict__ Wc1, const float* __restrict__ bc1,
                   const float* __restrict__ Wc2, const float* __restrict__ bc2,
                   const float* __restrict__ Wc3, const float* __restrict__ bc3,
                   float* __restrict__ out, int n)
{
    __shared__ short wsm[WTOT];
    __shared__ float act[8 * 16 * SA];
    const int tid = threadIdx.x;

    for (int t = tid; t < WTOT; t += MT) wsm[t] = 0;
    __syncthreads();

    for (int g = tid; g < 32 * 64; g += MT) {            // Wd1 (32,64) single
        const int k = g >> 6, nn = g & 63;
        wsm[OW1 + nn * SW1 + k] = f2bf(Wd1[g]);
    }
    for (int g = tid; g < 64 * 16; g += MT) {            // Wd2 (64,16) single
        const int k = g >> 4, nn = g & 15;
        wsm[OW2 + nn * SW + k] = f2bf(Wd2[g]);
    }
    for (int g = tid; g < 41 * 64; g += MT) {            // Wc1 (41,64) hi+lo
        const int k = g >> 6, nn = g & 63;
        const float w = Wc1[g];
        const unsigned short hh = f2bf(w);
        wsm[OC1H + nn * SW + k] = hh;
        wsm[OC1L + nn * SW + k] = f2bf(w - b2f(hh));
    }
    for (int g = tid; g < 64 * 64; g += MT) {            // Wc2 (64,64) hi+lo
        const int k = g >> 6, nn = g & 63;
        const float w = Wc2[g];
        const unsigned short hh = f2bf(w);
        wsm[OC2H + nn * SW + k] = hh;
        wsm[OC2L + nn * SW + k] = f2bf(w - b2f(hh));
    }
    for (int g = tid; g < 64 * 3; g += MT) {             // Wc3 (64,3) hi+lo
        const int k = g / 3, nn = g - 3 * k;
        const float w = Wc3[g];
        const unsigned short hh = f2bf(w);
        wsm[OC3H + nn * SW + k] = hh;
        wsm[OC3L + nn * SW + k] = f2bf(w - b2f(hh));
    }
    __syncthreads();

    const int wid = tid >> 6;              // 0..7
    const int lane = tid & 63;
    const int ln = lane & 15;
    const int qd = lane >> 4;
    float* A = act + wid * (16 * SA);

    // biases hoisted to registers (loop-invariant)
    float bd1v[4], bc1v[4], bc2v[4];
#pragma unroll
    for (int t = 0; t < 4; ++t) {
        bd1v[t] = bd1[t * 16 + ln];
        bc1v[t] = bc1[t * 16 + ln];
        bc2v[t] = bc2[t * 16 + ln];
    }
    const float bd2v = bd2[ln];
    const float bc3v = (ln < 3) ? bc3[ln] : 0.f;

#define LOAD_SPLIT(ah, al, k0)                                   \
    {                                                            \
        _Pragma("unroll")                                        \
        for (int j = 0; j < 8; ++j) {                            \
            const float v = A[ln * SA + (k0) + j];               \
            const unsigned short hb = f2bf(v);                   \
            ah[j] = (short)hb;                                   \
            al[j] = (short)f2bf(v - b2f(hb));                    \
        }                                                        \
    }

#define SPLIT_TILE(acc, ah0, ah1, al0, al1, OH, OL, row)                                          \
    {                                                                                             \
        const bf16x8 bh0 = *(const bf16x8*)&wsm[(OH) + (row) * SW + qd * 8];                      \
        const bf16x8 bh1 = *(const bf16x8*)&wsm[(OH) + (row) * SW + 32 + qd * 8];                 \
        const bf16x8 bl0 = *(const bf16x8*)&wsm[(OL) + (row) * SW + qd * 8];                      \
        const bf16x8 bl1 = *(const bf16x8*)&wsm[(OL) + (row) * SW + 32 + qd * 8];                 \
        acc = __builtin_amdgcn_mfma_f32_16x16x32_bf16(ah0, bh0, acc, 0, 0, 0);                    \
        acc = __builtin_amdgcn_mfma_f32_16x16x32_bf16(ah1, bh1, acc, 0, 0, 0);                    \
        acc = __builtin_amdgcn_mfma_f32_16x16x32_bf16(al0, bh0, acc, 0, 0, 0);                    \
        acc = __builtin_amdgcn_mfma_f32_16x16x32_bf16(al1, bh1, acc, 0, 0, 0);                    \
        acc = __builtin_amdgcn_mfma_f32_16x16x32_bf16(ah0, bl0, acc, 0, 0, 0);                    \
        acc = __builtin_amdgcn_mfma_f32_16x16x32_bf16(ah1, bl1, acc, 0, 0, 0);                    \
    }

    // ---- register prefetch of group 0's globals (packed bf16 planes) ----
    const int pt0 = blockIdx.x * (GROUPS * 128) + wid * 16 + ln;
    unsigned int xu0, xu1, xu2, xu3;
    float dq0, dq1, dq2;
    xu0 = wsp[(size_t)(qd * 4 + 0) * n + pt0];
    xu1 = wsp[(size_t)(qd * 4 + 1) * n + pt0];
    xu2 = wsp[(size_t)(qd * 4 + 2) * n + pt0];
    xu3 = wsp[(size_t)(qd * 4 + 3) * n + pt0];
    dq0 = dirp[3 * pt0 + 0];
    dq1 = dirp[3 * pt0 + 1];
    dq2 = dirp[3 * pt0 + 2];

#pragma unroll 1
    for (int grp = 0; grp < GROUPS; ++grp) {
        const int pt_base = blockIdx.x * (GROUPS * 128) + grp * 128 + wid * 16;
        const int pt = pt_base + ln;

        // consume prefetched globals (already bf16 bits — no converts)
        bf16x8 ax;
        ax[0] = (short)(xu0 & 0xffffu); ax[1] = (short)(xu0 >> 16);
        ax[2] = (short)(xu1 & 0xffffu); ax[3] = (short)(xu1 >> 16);
        ax[4] = (short)(xu2 & 0xffffu); ax[5] = (short)(xu2 >> 16);
        ax[6] = (short)(xu3 & 0xffffu); ax[7] = (short)(xu3 >> 16);
        const float ddx = dq0, ddy = dq1, ddz = dq2;

        // issue next group's globals now (consumed next iteration)
        if (grp + 1 < GROUPS) {
            const int ptn = pt + 128;
            xu0 = wsp[(size_t)(qd * 4 + 0) * n + ptn];
            xu1 = wsp[(size_t)(qd * 4 + 1) * n + ptn];
            xu2 = wsp[(size_t)(qd * 4 + 2) * n + ptn];
            xu3 = wsp[(size_t)(qd * 4 + 3) * n + ptn];
            dq0 = dirp[3 * ptn + 0];
            dq1 = dirp[3 * ptn + 1];
            dq2 = dirp[3 * ptn + 2];
        }

        // ---- d1: Y[16x64] = X @ Wd1 (single bf16) ----
        f32x4 yacc[4];
#pragma unroll
        for (int t = 0; t < 4; ++t) {
            const bf16x8 b = *(const bf16x8*)&wsm[OW1 + (t * 16 + ln) * SW1 + qd * 8];
            const float bv = bd1v[t];
            f32x4 acc = {bv, bv, bv, bv};
            yacc[t] = __builtin_amdgcn_mfma_f32_16x16x32_bf16(ax, b, acc, 0, 0, 0);
        }
#pragma unroll
        for (int t = 0; t < 4; ++t)
#pragma unroll
            for (int r = 0; r < 4; ++r)
                A[(qd * 4 + r) * SA + t * 16 + ln] = fmaxf(yacc[t][r], 0.f);   // fp32

        // ---- d2: D[16x16] = relu(Y) @ Wd2 (single bf16) ----
        {
            bf16x8 a0, a1;
#pragma unroll
            for (int j = 0; j < 8; ++j) a0[j] = (short)f2bf(A[ln * SA + qd * 8 + j]);
#pragma unroll
            for (int j = 0; j < 8; ++j) a1[j] = (short)f2bf(A[ln * SA + 32 + qd * 8 + j]);
            const bf16x8 b0 = *(const bf16x8*)&wsm[OW2 + ln * SW + qd * 8];
            const bf16x8 b1 = *(const bf16x8*)&wsm[OW2 + ln * SW + 32 + qd * 8];
            const float bv = bd2v;
            f32x4 acc = {bv, bv, bv, bv};
            acc = __builtin_amdgcn_mfma_f32_16x16x32_bf16(a0, b0, acc, 0, 0, 0);
            acc = __builtin_amdgcn_mfma_f32_16x16x32_bf16(a1, b1, acc, 0, 0, 0);
            if (ln == 15) {
#pragma unroll
                for (int r = 0; r < 4; ++r)
                    out[3 * n + pt_base + qd * 4 + r] = fmaxf(acc[r], 0.f);    // sigma
            }
#pragma unroll
            for (int r = 0; r < 4; ++r)
                A[(qd * 4 + r) * SA + ln] = acc[r];        // raw D fp32, k=0..15
        }

        // ---- SH -> act fp32, k=16..40 (k=41..63 stale, Wc1 rows zeroed) ----
        // Fully unrolled + predicated: sh[] static-indexed -> stays in VGPRs.
        {
            float sh[25];
            SH_BLOCK(sh, ddx, ddy, ddz)
#pragma unroll
            for (int i = 0; i < 25; ++i)
                if ((i & 3) == qd)
                    A[ln * SA + 16 + i] = sh[i];
        }

        // ---- c1: H1 = [D|SH|0] @ Wc1 (split) ----
        {
            bf16x8 ah0, ah1, al0, al1;
            LOAD_SPLIT(ah0, al0, qd * 8)
            LOAD_SPLIT(ah1, al1, 32 + qd * 8)
            f32x4 hacc[4];
#pragma unroll
            for (int t = 0; t < 4; ++t) {
                const float bv = bc1v[t];
                f32x4 acc = {bv, bv, bv, bv};
                SPLIT_TILE(acc, ah0, ah1, al0, al1, OC1H, OC1L, t * 16 + ln)
                hacc[t] = acc;
            }
#pragma unroll
            for (int t = 0; t < 4; ++t)
#pragma unroll
                for (int r = 0; r < 4; ++r)
                    A[(qd * 4 + r) * SA + t * 16 + ln] = fmaxf(hacc[t][r], 0.f);
        }

        // ---- c2: H2 = relu(H1) @ Wc2 (split) ----
        {
            bf16x8 ah0, ah1, al0, al1;
            LOAD_SPLIT(ah0, al0, qd * 8)
            LOAD_SPLIT(ah1, al1, 32 + qd * 8)
            f32x4 hacc[4];
#pragma unroll
            for (int t = 0; t < 4; ++t) {
                const float bv = bc2v[t];
                f32x4 acc = {bv, bv, bv, bv};
                SPLIT_TILE(acc, ah0, ah1, al0, al1, OC2H, OC2L, t * 16 + ln)
                hacc[t] = acc;
            }
#pragma unroll
            for (int t = 0; t < 4; ++t)
#pragma unroll
                for (int r = 0; r < 4; ++r)
                    A[(qd * 4 + r) * SA + t * 16 + ln] = fmaxf(hacc[t][r], 0.f);
        }

        // ---- c3 + sigmoid: R = relu(H2) @ Wc3 (split) ----
        {
            bf16x8 ah0, ah1, al0, al1;
            LOAD_SPLIT(ah0, al0, qd * 8)
            LOAD_SPLIT(ah1, al1, 32 + qd * 8)
            const float bv = bc3v;
            f32x4 acc = {bv, bv, bv, bv};
            SPLIT_TILE(acc, ah0, ah1, al0, al1, OC3H, OC3L, ln)
            if (ln < 3) {
#pragma unroll
                for (int r = 0; r < 4; ++r)
                    out[3 * (pt_base + qd * 4 + r) + ln] = 1.f / (1.f + expf(-acc[r]));
            }
        }
    }
}

// ------------------------------------------------------------------
// Fallback: round-1 fused kernel (if ws too small / n not 2^19) — proven
// ------------------------------------------------------------------
__global__ __launch_bounds__(256)
void nerf_fused(const float* __restrict__ pos,
                const float* __restrict__ dirp,
                const float* __restrict__ tables,
                const float* __restrict__ Wd1, const float* __restrict__ bd1,
                const float* __restrict__ Wd2, const float* __restrict__ bd2,
                const float* __restrict__ Wc1, const float* __restrict__ bc1,
                const float* __restrict__ Wc2, const float* __restrict__ bc2,
                const float* __restrict__ Wc3, const float* __restrict__ bc3,
                float* __restrict__ out, int n)
{
    const int idx = blockIdx.x * blockDim.x + threadIdx.x;
    if (idx >= n) return;
    const float px = pos[3 * idx + 0], py = pos[3 * idx + 1], pz = pos[3 * idx + 2];
    float y[64];
#pragma unroll
    for (int j = 0; j < 64; ++j) y[j] = bd1[j];
#pragma unroll
    for (int l = 0; l < LEVELS; ++l) {
        const float resf = (float)(16 << l);
        const float tx = px * resf, ty = py * resf, tz = pz * resf;
        const float fx = floorf(tx), fy = floorf(ty), fz = floorf(tz);
        const float wx = tx - fx, wy = ty - fy, wz = tz - fz;
        const unsigned ix = (unsigned)(int)fx, iy = (unsigned)(int)fy, iz = (unsigned)(int)fz;
        const unsigned hy0 = iy * 2654435761u, hy1 = hy0 + 2654435761u;
        const unsigned hz0 = iz * 805459861u,  hz1 = hz0 + 805459861u;
        const unsigned ix1 = ix + 1u;
        const float2* tb = (const float2*)tables + (size_t)l * TBL;
        const float2 e000 = tb[(ix  ^ hy0 ^ hz0) & TMASK];
        const float2 e001 = tb[(ix  ^ hy0 ^ hz1) & TMASK];
        const float2 e010 = tb[(ix  ^ hy1 ^ hz0) & TMASK];
        const float2 e011 = tb[(ix  ^ hy1 ^ hz1) & TMASK];
        const float2 e100 = tb[(ix1 ^ hy0 ^ hz0) & TMASK];
        const float2 e101 = tb[(ix1 ^ hy0 ^ hz1) & TMASK];
        const float2 e110 = tb[(ix1 ^ hy1 ^ hz0) & TMASK];
        const float2 e111 = tb[(ix1 ^ hy1 ^ hz1) & TMASK];
        const float ux = 1.f - wx, uy = 1.f - wy, uz = 1.f - wz;
        const float c000 = ux*uy*uz, c001 = ux*uy*wz, c010 = ux*wy*uz, c011 = ux*wy*wz;
        const float c100 = wx*uy*uz, c101 = wx*uy*wz, c110 = wx*wy*uz, c111 = wx*wy*wz;
        float f0 = e000.x*c000, f1 = e000.y*c000;
        f0 = fmaf(e001.x,c001,f0); f1 = fmaf(e001.y,c001,f1);
        f0 = fmaf(e010.x,c010,f0); f1 = fmaf(e010.y,c010,f1);
        f0 = fmaf(e011.x,c011,f0); f1 = fmaf(e011.y,c011,f1);
        f0 = fmaf(e100.x,c100,f0); f1 = fmaf(e100.y,c100,f1);
        f0 = fmaf(e101.x,c101,f0); f1 = fmaf(e101.y,c101,f1);
        f0 = fmaf(e110.x,c110,f0); f1 = fmaf(e110.y,c110,f1);
        f0 = fmaf(e111.x,c111,f0); f1 = fmaf(e111.y,c111,f1);
        const float* w0 = Wd1 + (size_t)(2 * l) * 64;
#pragma unroll
        for (int j = 0; j < 64; ++j)
            y[j] = fmaf(f0, w0[j], fmaf(f1, w0[64 + j], y[j]));
    }
    float d[16];
#pragma unroll
    for (int k = 0; k < 16; ++k) d[k] = bd2[k];
#pragma unroll
    for (int j = 0; j < 64; ++j) {
        const float a = fmaxf(y[j], 0.f);
#pragma unroll
        for (int k = 0; k < 16; ++k) d[k] = fmaf(a, Wd2[j * 16 + k], d[k]);
    }
    out[3 * n + idx] = fmaxf(d[15], 0.f);
    const float dx = dirp[3*idx], dy = dirp[3*idx+1], dz = dirp[3*idx+2];
    float sh[25];
    SH_BLOCK(sh, dx, dy, dz)
    float h1[64];
#pragma unroll
    for (int j = 0; j < 64; ++j) h1[j] = bc1[j];
#pragma unroll
    for (int i = 0; i < 16; ++i) {
#pragma unroll
        for (int j = 0; j < 64; ++j) h1[j] = fmaf(d[i], Wc1[i * 64 + j], h1[j]);
    }
#pragma unroll
    for (int s = 0; s < 25; ++s) {
#pragma unroll
        for (int j = 0; j < 64; ++j) h1[j] = fmaf(sh[s], Wc1[(16 + s) * 64 + j], h1[j]);
    }
    float h2[64];
#pragma unroll
    for (int j = 0; j < 64; ++j) h2[j] = bc2[j];
#pragma unroll
    for (int i = 0; i < 64; ++i) {
        const float a = fmaxf(h1[i], 0.f);
#pragma unroll
        for (int j = 0; j < 64; ++j) h2[j] = fmaf(a, Wc2[i * 64 + j], h2[j]);
    }
    float r0 = bc3[0], r1 = bc3[1], r2 = bc3[2];
#pragma unroll
    for (int j = 0; j < 64; ++j) {
        const float a = fmaxf(h2[j], 0.f);
        r0 = fmaf(a, Wc3[j * 3 + 0], r0);
        r1 = fmaf(a, Wc3[j * 3 + 1], r1);
        r2 = fmaf(a, Wc3[j * 3 + 2], r2);
    }
    out[3 * idx + 0] = 1.f / (1.f + expf(-r0));
    out[3 * idx + 1] = 1.f / (1.f + expf(-r1));
    out[3 * idx + 2] = 1.f / (1.f + expf(-r2));
}

extern "C" void kernel_launch(void* const* d_in, const int* in_sizes, int n_in,
                              void* d_out, int out_size, void* d_ws, size_t ws_size,
                              hipStream_t stream) {
    const float* pos    = (const float*)d_in[0];
    const float* dir    = (const float*)d_in[1];
    const float* tables = (const float*)d_in[2];
    const float* Wd1 = (const float*)d_in[3];
    const float* bd1 = (const float*)d_in[4];
    const float* Wd2 = (const float*)d_in[5];
    const float* bd2 = (const float*)d_in[6];
    const float* Wc1 = (const float*)d_in[7];
    const float* bc1 = (const float*)d_in[8];
    const float* Wc2 = (const float*)d_in[9];
    const float* bc2 = (const float*)d_in[10];
    const float* Wc3 = (const float*)d_in[11];
    const float* bc3 = (const float*)d_in[12];

    const int n = in_sizes[0] / 3;
    const int blocks = (n + 255) / 256;

    // workspace layout: [0, n*64) packed-bf16 feature planes;
    //                   [n*64, n*128) packed-bf16 tables (16*TBL uints)
    if (ws_size >= (size_t)n * 128 && n == 524288) {
        unsigned int* wsp  = (unsigned int*)d_ws;
        unsigned int* tb16 = (unsigned int*)((char*)d_ws + (size_t)n * 64);
        const int total = LEVELS * TBL;
        cvt_tables<<<total / 1024, 256, 0, stream>>>(tables, tb16, total);
        ngp_encode_lvl<<<16 * blocks, 256, 0, stream>>>(pos, tb16, wsp, n);
        ngp_mlp_mfma4<<<n / (128 * GROUPS), MT, 0, stream>>>((const unsigned int*)wsp, dir,
                                                             Wd1, bd1, Wd2, bd2,
                                                             Wc1, bc1, Wc2, bc2, Wc3, bc3,
                                                             (float*)d_out, n);
    } else {
        nerf_fused<<<blocks, 256, 0, stream>>>(pos, dir, tables,
                                               Wd1, bd1, Wd2, bd2,
                                               Wc1, bc1, Wc2, bc2, Wc3, bc3,
                                               (float*)d_out, n);
    }
}

// Round 4
// 360.736 us; speedup vs baseline: 1.3790x; 1.0002x over previous
//
#include <hip/hip_runtime.h>
#include <math.h>

#define LEVELS 16
#define TBL 524288          // 2^19 entries per level
#define TMASK (TBL - 1)

typedef short bf16x8 __attribute__((ext_vector_type(8)));
typedef float f32x4  __attribute__((ext_vector_type(4)));
typedef float fvec4  __attribute__((ext_vector_type(4)));
typedef unsigned int uvec4 __attribute__((ext_vector_type(4)));

static __device__ __forceinline__ unsigned short f2bf(float x) {
    unsigned u = __float_as_uint(x);
    u += 0x7fffu + ((u >> 16) & 1u);    // RNE
    return (unsigned short)(u >> 16);
}
static __device__ __forceinline__ float b2f(unsigned short h) {
    return __uint_as_float(((unsigned)h) << 16);
}

// SH degree-4 block, constants computed exactly as round-1 (verified correct).
#define SH_BLOCK(sh, dx, dy, dz)                                                          \
    const float x2 = dx * dx, y2 = dy * dy, z2 = dz * dz;                                 \
    const float xy = dx * dy, xz = dx * dz, yz = dy * dz;                                 \
    const float x4 = x2 * x2, y4 = y2 * y2;                                               \
    const float c0  = (float)(0.5 * sqrt(1.0 / M_PI));                                    \
    const float c1  = (float)(0.5 * sqrt(3.0 / M_PI));                                    \
    const float sub = (float)(0.25 * sqrt(5.0 / M_PI));                                   \
    const float v1  = (float)(0.25 * sqrt(15.0 / M_PI));                                  \
    const float v2  = (float)(0.5 * sqrt(15.0 / M_PI));                                   \
    const float v3  = (float)(0.75 * sqrt(5.0 / M_PI));                                   \
    const float w1c = (float)(0.25 * sqrt(105.0 / M_PI));                                 \
    const float w2c = (float)(0.5 * sqrt(105.0 / M_PI));                                  \
    const float w3c = (float)(0.25 * sqrt(35.0 / (2.0 * M_PI)));                          \
    const float w4c = (float)(0.5 * sqrt(7.0 / (6.0 * M_PI)));                            \
    sh[0] = c0;                                                                           \
    sh[1] = -c1 * dy;                                                                     \
    sh[2] =  c1 * dz;                                                                     \
    sh[3] = -c1 * dx;                                                                     \
    sh[4] =  v2 * xy;                                                                     \
    sh[5] = -v2 * yz;                                                                     \
    sh[6] =  v3 * z2 - sub;                                                               \
    sh[7] = -v2 * xz;                                                                     \
    sh[8] =  v1 * x2 - v1 * y2;                                                           \
    sh[9]  = -w3c * dy * (3.0f * x2 - y2);                                                \
    sh[10] =  w2c * xy * dz;                                                              \
    sh[11] =  w4c * dy * (1.5f - 7.5f * z2);                                              \
    sh[12] =  1.24392110863372f * dz * (1.5f * z2 - 0.5f) - 0.497568443453487f * dz;      \
    sh[13] =  w4c * dx * (1.5f - 7.5f * z2);                                              \
    sh[14] =  w1c * dz * (x2 - y2);                                                       \
    sh[15] = -w3c * dx * (x2 - 3.0f * y2);                                                \
    sh[16] =  2.5033429417967f * xy * (x2 - y2);                                          \
    sh[17] = -1.77013076977993f * yz * (3.0f * x2 - y2);                                  \
    sh[18] =  0.126156626101008f * xy * (52.5f * z2 - 7.5f);                              \
    sh[19] =  0.267618617422916f * dy * (2.33333333333333f * dz * (1.5f - 7.5f * z2) + 4.0f * dz); \
    sh[20] =  1.48099765681286f * dz * (1.66666666666667f * dz * (1.5f * z2 - 0.5f) - 0.666666666666667f * dz) \
              - 0.952069922236839f * z2 + 0.317356640745613f;                             \
    sh[21] =  0.267618617422916f * dx * (2.33333333333333f * dz * (1.5f - 7.5f * z2) + 4.0f * dz); \
    sh[22] =  0.063078313050504f * (x2 - y2) * (52.5f * z2 - 7.5f);                       \
    sh[23] = -1.77013076977993f * xz * (x2 - 3.0f * y2);                                  \
    sh[24] = -3.75501441269506f * x2 * y2 + 0.625835735449176f * x4 + 0.625835735449176f * y4;

// ------------------------------------------------------------------
// Kernel 0: pack fp32 tables -> bf16x2 (one uint per entry).
// ------------------------------------------------------------------
__global__ __launch_bounds__(256)
void cvt_tables(const float* __restrict__ tables,
                unsigned int* __restrict__ tb16, int total)
{
    const int i = (blockIdx.x * 256 + threadIdx.x) * 4;   // 4 entries/thread
    if (i >= total) return;
    const fvec4 a = __builtin_nontemporal_load((const fvec4*)(tables + 2 * (size_t)i));
    const fvec4 b = __builtin_nontemporal_load((const fvec4*)(tables + 2 * (size_t)i) + 1);
    uvec4 o;
    o.x = ((unsigned)f2bf(a.y) << 16) | f2bf(a.x);
    o.y = ((unsigned)f2bf(a.w) << 16) | f2bf(a.z);
    o.z = ((unsigned)f2bf(b.y) << 16) | f2bf(b.x);
    o.w = ((unsigned)f2bf(b.w) << 16) | f2bf(b.z);
    __builtin_nontemporal_store(o, (uvec4*)&tb16[i]);
}

// ------------------------------------------------------------------
// Kernel 1: hash-grid gather, level<->XCD affinity (unchanged R13:
// packed-bf16 table + even-ix x-pair merge). 156 us, FETCH ~63 MB.
// ------------------------------------------------------------------
__global__ __launch_bounds__(256)
void ngp_encode_lvl(const float* __restrict__ pos,
                    const unsigned int* __restrict__ tb16,
                    unsigned int* __restrict__ wsp, int n)
{
    const int b = blockIdx.x;
    const int p = b & 7;
    const int h = b >> 14;                 // 16384 blocks per half (n = 2^19)
    const int l = 2 * p + h;
    const int c = (b & 16383) >> 3;
    const int idx = c * 256 + threadIdx.x;
    if (idx >= n || l >= LEVELS) return;

    const float px = pos[3 * idx + 0];
    const float py = pos[3 * idx + 1];
    const float pz = pos[3 * idx + 2];

    const float resf = (float)(16 << l);
    const float tx = px * resf, ty = py * resf, tz = pz * resf;
    const float fx = floorf(tx), fy = floorf(ty), fz = floorf(tz);
    const float wx = tx - fx, wy = ty - fy, wz = tz - fz;
    const unsigned ix = (unsigned)(int)fx;
    const unsigned iy = (unsigned)(int)fy;
    const unsigned iz = (unsigned)(int)fz;
    const unsigned hy0 = iy * 2654435761u, hy1 = hy0 + 2654435761u;
    const unsigned hz0 = iz * 805459861u,  hz1 = hz0 + 805459861u;
    const unsigned ix1 = ix + 1u;

    const unsigned int* tb = tb16 + (size_t)l * TBL;
    const unsigned hA = hy0 ^ hz0;        // (y=0,z=0)
    const unsigned hB = hy0 ^ hz1;        // (y=0,z=1)
    const unsigned hC = hy1 ^ hz0;        // (y=1,z=0)
    const unsigned hD = hy1 ^ hz1;        // (y=1,z=1)

    unsigned eA0, eA1, eB0, eB1, eC0, eC1, eD0, eD1;   // e{combo}{x}
    if ((ix & 1u) == 0u) {
        // even ix: {ix^h, (ix+1)^h} = {m, m^1} -> one aligned 8B load
        const uint2 pA = *(const uint2*)&tb[((ix ^ hA) & TMASK) & ~1u];
        const uint2 pB = *(const uint2*)&tb[((ix ^ hB) & TMASK) & ~1u];
        const uint2 pC = *(const uint2*)&tb[((ix ^ hC) & TMASK) & ~1u];
        const uint2 pD = *(const uint2*)&tb[((ix ^ hD) & TMASK) & ~1u];
        const unsigned sA = hA & 1u, sB = hB & 1u, sC = hC & 1u, sD = hD & 1u;
        eA0 = sA ? pA.y : pA.x;  eA1 = sA ? pA.x : pA.y;
        eB0 = sB ? pB.y : pB.x;  eB1 = sB ? pB.x : pB.y;
        eC0 = sC ? pC.y : pC.x;  eC1 = sC ? pC.x : pC.y;
        eD0 = sD ? pD.y : pD.x;  eD1 = sD ? pD.x : pD.y;
    } else {
        eA0 = tb[(ix  ^ hA) & TMASK];  eA1 = tb[(ix1 ^ hA) & TMASK];
        eB0 = tb[(ix  ^ hB) & TMASK];  eB1 = tb[(ix1 ^ hB) & TMASK];
        eC0 = tb[(ix  ^ hC) & TMASK];  eC1 = tb[(ix1 ^ hC) & TMASK];
        eD0 = tb[(ix  ^ hD) & TMASK];  eD1 = tb[(ix1 ^ hD) & TMASK];
    }

#define UNPX(e) __uint_as_float((e) << 16)
#define UNPY(e) __uint_as_float((e) & 0xffff0000u)

    const float ux = 1.f - wx, uy = 1.f - wy, uz = 1.f - wz;
    const float c000 = ux * uy * uz, c001 = ux * uy * wz;
    const float c010 = ux * wy * uz, c011 = ux * wy * wz;
    const float c100 = wx * uy * uz, c101 = wx * uy * wz;
    const float c110 = wx * wy * uz, c111 = wx * wy * wz;

    float f0 = UNPX(eA0) * c000, f1 = UNPY(eA0) * c000;
    f0 = fmaf(UNPX(eB0), c001, f0); f1 = fmaf(UNPY(eB0), c001, f1);
    f0 = fmaf(UNPX(eC0), c010, f0); f1 = fmaf(UNPY(eC0), c010, f1);
    f0 = fmaf(UNPX(eD0), c011, f0); f1 = fmaf(UNPY(eD0), c011, f1);
    f0 = fmaf(UNPX(eA1), c100, f0); f1 = fmaf(UNPY(eA1), c100, f1);
    f0 = fmaf(UNPX(eB1), c101, f0); f1 = fmaf(UNPY(eB1), c101, f1);
    f0 = fmaf(UNPX(eC1), c110, f0); f1 = fmaf(UNPY(eC1), c110, f1);
    f0 = fmaf(UNPX(eD1), c111, f0); f1 = fmaf(UNPY(eD1), c111, f1);

    const unsigned int h0 = f2bf(f0);
    const unsigned int h1 = f2bf(f1);
    __builtin_nontemporal_store((h1 << 16) | h0, &wsp[(size_t)l * n + idx]);
}

// ------------------------------------------------------------------
// Kernel 2: split-precision MFMA MLP, persistent blocks.
// R14: __launch_bounds__(512, 2). The old (512,4) capped VGPR at 128,
// below the c1/c2 live set (~135+): compiler spilled INSIDE the group
// loop -> ~32 MB scratch round-trip per dispatch (R3 counters: FETCH
// 74 MB vs 41 ideal, WRITE 39 vs 8.4, VALUBusy 1.9%). Cap 256 ->
// clean registers, 8 waves/CU (1 block resident, 2 rounds).
// SPLIT_TILE also reordered: low-half B-tiles loaded after the first
// 4 MFMAs (same accumulation order, bit-identical; -8 VGPR peak).
// ------------------------------------------------------------------
#define MT   512
#define GROUPS 8
#define SW1  32                  // Wd1 k-stride (shorts), rows 16B-aligned
#define SW   72                  // 64-k weight stride (shorts), rows 16B-aligned
#define SA   65                  // act k-stride (floats)
#define OW1  0                   // 64*32 = 2048
#define OW2  2048                // 16*72 = 1152
#define OC1H 3200                // 64*72 = 4608
#define OC1L 7808
#define OC2H 12416
#define OC2L 17024
#define OC3H 21632               // 16*72 = 1152
#define OC3L 22784
#define WTOT 23936               // shorts = 47,872 B; + act 33,280 B = 81,152 B

__global__ __launch_bounds__(512, 2)
void ngp_mlp_mfma4(const unsigned int* __restrict__ wsp,
                   const float* __restrict__ dirp,
                   const float* __restrict__ Wd1, const float* __restrict__ bd1,
                   const float* __restrict__ Wd2, const float* __restrict__ bd2,
                   const float* __restrict__ Wc1, const float* __restrict__ bc1,
                   const float* __restrict__ Wc2, const float* __restrict__ bc2,
                   const float* __restrict__ Wc3, const float* __restrict__ bc3,
                   float* __restrict__ out, int n)
{
    __shared__ short wsm[WTOT];
    __shared__ float act[8 * 16 * SA];
    const int tid = threadIdx.x;

    for (int t = tid; t < WTOT; t += MT) wsm[t] = 0;
    __syncthreads();

    for (int g = tid; g < 32 * 64; g += MT) {            // Wd1 (32,64) single
        const int k = g >> 6, nn = g & 63;
        wsm[OW1 + nn * SW1 + k] = f2bf(Wd1[g]);
    }
    for (int g = tid; g < 64 * 16; g += MT) {            // Wd2 (64,16) single
        const int k = g >> 4, nn = g & 15;
        wsm[OW2 + nn * SW + k] = f2bf(Wd2[g]);
    }
    for (int g = tid; g < 41 * 64; g += MT) {            // Wc1 (41,64) hi+lo
        const int k = g >> 6, nn = g & 63;
        const float w = Wc1[g];
        const unsigned short hh = f2bf(w);
        wsm[OC1H + nn * SW + k] = hh;
        wsm[OC1L + nn * SW + k] = f2bf(w - b2f(hh));
    }
    for (int g = tid; g < 64 * 64; g += MT) {            // Wc2 (64,64) hi+lo
        const int k = g >> 6, nn = g & 63;
        const float w = Wc2[g];
        const unsigned short hh = f2bf(w);
        wsm[OC2H + nn * SW + k] = hh;
        wsm[OC2L + nn * SW + k] = f2bf(w - b2f(hh));
    }
    for (int g = tid; g < 64 * 3; g += MT) {             // Wc3 (64,3) hi+lo
        const int k = g / 3, nn = g - 3 * k;
        const float w = Wc3[g];
        const unsigned short hh = f2bf(w);
        wsm[OC3H + nn * SW + k] = hh;
        wsm[OC3L + nn * SW + k] = f2bf(w - b2f(hh));
    }
    __syncthreads();

    const int wid = tid >> 6;              // 0..7
    const int lane = tid & 63;
    const int ln = lane & 15;
    const int qd = lane >> 4;
    float* A = act + wid * (16 * SA);

    // biases hoisted to registers (loop-invariant)
    float bd1v[4], bc1v[4], bc2v[4];
#pragma unroll
    for (int t = 0; t < 4; ++t) {
        bd1v[t] = bd1[t * 16 + ln];
        bc1v[t] = bc1[t * 16 + ln];
        bc2v[t] = bc2[t * 16 + ln];
    }
    const float bd2v = bd2[ln];
    const float bc3v = (ln < 3) ? bc3[ln] : 0.f;

#define LOAD_SPLIT(ah, al, k0)                                   \
    {                                                            \
        _Pragma("unroll")                                        \
        for (int j = 0; j < 8; ++j) {                            \
            const float v = A[ln * SA + (k0) + j];               \
            const unsigned short hb = f2bf(v);                   \
            ah[j] = (short)hb;                                   \
            al[j] = (short)f2bf(v - b2f(hb));                    \
        }                                                        \
    }

// hi-half B-tiles first, 4 MFMAs, then lo-half B-tiles, 2 MFMAs:
// same accumulation order as before (bit-identical), but only 2
// B-tiles (8 VGPR) live at any point instead of 4 (16).
#define SPLIT_TILE(acc, ah0, ah1, al0, al1, OH, OL, row)                                          \
    {                                                                                             \
        const bf16x8 bh0 = *(const bf16x8*)&wsm[(OH) + (row) * SW + qd * 8];                      \
        const bf16x8 bh1 = *(const bf16x8*)&wsm[(OH) + (row) * SW + 32 + qd * 8];                 \
        acc = __builtin_amdgcn_mfma_f32_16x16x32_bf16(ah0, bh0, acc, 0, 0, 0);                    \
        acc = __builtin_amdgcn_mfma_f32_16x16x32_bf16(ah1, bh1, acc, 0, 0, 0);                    \
        acc = __builtin_amdgcn_mfma_f32_16x16x32_bf16(al0, bh0, acc, 0, 0, 0);                    \
        acc = __builtin_amdgcn_mfma_f32_16x16x32_bf16(al1, bh1, acc, 0, 0, 0);                    \
        const bf16x8 bl0 = *(const bf16x8*)&wsm[(OL) + (row) * SW + qd * 8];                      \
        const bf16x8 bl1 = *(const bf16x8*)&wsm[(OL) + (row) * SW + 32 + qd * 8];                 \
        acc = __builtin_amdgcn_mfma_f32_16x16x32_bf16(ah0, bl0, acc, 0, 0, 0);                    \
        acc = __builtin_amdgcn_mfma_f32_16x16x32_bf16(ah1, bl1, acc, 0, 0, 0);                    \
    }

    // ---- register prefetch of group 0's globals (packed bf16 planes) ----
    const int pt0 = blockIdx.x * (GROUPS * 128) + wid * 16 + ln;
    unsigned int xu0, xu1, xu2, xu3;
    float dq0, dq1, dq2;
    xu0 = wsp[(size_t)(qd * 4 + 0) * n + pt0];
    xu1 = wsp[(size_t)(qd * 4 + 1) * n + pt0];
    xu2 = wsp[(size_t)(qd * 4 + 2) * n + pt0];
    xu3 = wsp[(size_t)(qd * 4 + 3) * n + pt0];
    dq0 = dirp[3 * pt0 + 0];
    dq1 = dirp[3 * pt0 + 1];
    dq2 = dirp[3 * pt0 + 2];

#pragma unroll 1
    for (int grp = 0; grp < GROUPS; ++grp) {
        const int pt_base = blockIdx.x * (GROUPS * 128) + grp * 128 + wid * 16;
        const int pt = pt_base + ln;

        // consume prefetched globals (already bf16 bits — no converts)
        bf16x8 ax;
        ax[0] = (short)(xu0 & 0xffffu); ax[1] = (short)(xu0 >> 16);
        ax[2] = (short)(xu1 & 0xffffu); ax[3] = (short)(xu1 >> 16);
        ax[4] = (short)(xu2 & 0xffffu); ax[5] = (short)(xu2 >> 16);
        ax[6] = (short)(xu3 & 0xffffu); ax[7] = (short)(xu3 >> 16);
        const float ddx = dq0, ddy = dq1, ddz = dq2;

        // issue next group's globals now (consumed next iteration)
        if (grp + 1 < GROUPS) {
            const int ptn = pt + 128;
            xu0 = wsp[(size_t)(qd * 4 + 0) * n + ptn];
            xu1 = wsp[(size_t)(qd * 4 + 1) * n + ptn];
            xu2 = wsp[(size_t)(qd * 4 + 2) * n + ptn];
            xu3 = wsp[(size_t)(qd * 4 + 3) * n + ptn];
            dq0 = dirp[3 * ptn + 0];
            dq1 = dirp[3 * ptn + 1];
            dq2 = dirp[3 * ptn + 2];
        }

        // ---- d1: Y[16x64] = X @ Wd1 (single bf16) ----
        f32x4 yacc[4];
#pragma unroll
        for (int t = 0; t < 4; ++t) {
            const bf16x8 b = *(const bf16x8*)&wsm[OW1 + (t * 16 + ln) * SW1 + qd * 8];
            const float bv = bd1v[t];
            f32x4 acc = {bv, bv, bv, bv};
            yacc[t] = __builtin_amdgcn_mfma_f32_16x16x32_bf16(ax, b, acc, 0, 0, 0);
        }
#pragma unroll
        for (int t = 0; t < 4; ++t)
#pragma unroll
            for (int r = 0; r < 4; ++r)
                A[(qd * 4 + r) * SA + t * 16 + ln] = fmaxf(yacc[t][r], 0.f);   // fp32

        // ---- d2: D[16x16] = relu(Y) @ Wd2 (single bf16) ----
        {
            bf16x8 a0, a1;
#pragma unroll
            for (int j = 0; j < 8; ++j) a0[j] = (short)f2bf(A[ln * SA + qd * 8 + j]);
#pragma unroll
            for (int j = 0; j < 8; ++j) a1[j] = (short)f2bf(A[ln * SA + 32 + qd * 8 + j]);
            const bf16x8 b0 = *(const bf16x8*)&wsm[OW2 + ln * SW + qd * 8];
            const bf16x8 b1 = *(const bf16x8*)&wsm[OW2 + ln * SW + 32 + qd * 8];
            const float bv = bd2v;
            f32x4 acc = {bv, bv, bv, bv};
            acc = __builtin_amdgcn_mfma_f32_16x16x32_bf16(a0, b0, acc, 0, 0, 0);
            acc = __builtin_amdgcn_mfma_f32_16x16x32_bf16(a1, b1, acc, 0, 0, 0);
            if (ln == 15) {
#pragma unroll
                for (int r = 0; r < 4; ++r)
                    out[3 * n + pt_base + qd * 4 + r] = fmaxf(acc[r], 0.f);    // sigma
            }
#pragma unroll
            for (int r = 0; r < 4; ++r)
                A[(qd * 4 + r) * SA + ln] = acc[r];        // raw D fp32, k=0..15
        }

        // ---- SH -> act fp32, k=16..40 (k=41..63 stale, Wc1 rows zeroed) ----
        // Fully unrolled + predicated: sh[] static-indexed -> stays in VGPRs.
        {
            float sh[25];
            SH_BLOCK(sh, ddx, ddy, ddz)
#pragma unroll
            for (int i = 0; i < 25; ++i)
                if ((i & 3) == qd)
                    A[ln * SA + 16 + i] = sh[i];
        }

        // ---- c1: H1 = [D|SH|0] @ Wc1 (split) ----
        {
            bf16x8 ah0, ah1, al0, al1;
            LOAD_SPLIT(ah0, al0, qd * 8)
            LOAD_SPLIT(ah1, al1, 32 + qd * 8)
            f32x4 hacc[4];
#pragma unroll
            for (int t = 0; t < 4; ++t) {
                const float bv = bc1v[t];
                f32x4 acc = {bv, bv, bv, bv};
                SPLIT_TILE(acc, ah0, ah1, al0, al1, OC1H, OC1L, t * 16 + ln)
                hacc[t] = acc;
            }
#pragma unroll
            for (int t = 0; t < 4; ++t)
#pragma unroll
                for (int r = 0; r < 4; ++r)
                    A[(qd * 4 + r) * SA + t * 16 + ln] = fmaxf(hacc[t][r], 0.f);
        }

        // ---- c2: H2 = relu(H1) @ Wc2 (split) ----
        {
            bf16x8 ah0, ah1, al0, al1;
            LOAD_SPLIT(ah0, al0, qd * 8)
            LOAD_SPLIT(ah1, al1, 32 + qd * 8)
            f32x4 hacc[4];
#pragma unroll
            for (int t = 0; t < 4; ++t) {
                const float bv = bc2v[t];
                f32x4 acc = {bv, bv, bv, bv};
                SPLIT_TILE(acc, ah0, ah1, al0, al1, OC2H, OC2L, t * 16 + ln)
                hacc[t] = acc;
            }
#pragma unroll
            for (int t = 0; t < 4; ++t)
#pragma unroll
                for (int r = 0; r < 4; ++r)
                    A[(qd * 4 + r) * SA + t * 16 + ln] = fmaxf(hacc[t][r], 0.f);
        }

        // ---- c3 + sigmoid: R = relu(H2) @ Wc3 (split) ----
        {
            bf16x8 ah0, ah1, al0, al1;
            LOAD_SPLIT(ah0, al0, qd * 8)
            LOAD_SPLIT(ah1, al1, 32 + qd * 8)
            const float bv = bc3v;
            f32x4 acc = {bv, bv, bv, bv};
            SPLIT_TILE(acc, ah0, ah1, al0, al1, OC3H, OC3L, ln)
            if (ln < 3) {
#pragma unroll
                for (int r = 0; r < 4; ++r)
                    out[3 * (pt_base + qd * 4 + r) + ln] = 1.f / (1.f + expf(-acc[r]));
            }
        }
    }
}

// ------------------------------------------------------------------
// Fallback: round-1 fused kernel (if ws too small / n not 2^19) — proven
// ------------------------------------------------------------------
__global__ __launch_bounds__(256)
void nerf_fused(const float* __restrict__ pos,
                const float* __restrict__ dirp,
                const float* __restrict__ tables,
                const float* __restrict__ Wd1, const float* __restrict__ bd1,
                const float* __restrict__ Wd2, const float* __restrict__ bd2,
                const float* __restrict__ Wc1, const float* __restrict__ bc1,
                const float* __restrict__ Wc2, const float* __restrict__ bc2,
                const float* __restrict__ Wc3, const float* __restrict__ bc3,
                float* __restrict__ out, int n)
{
    const int idx = blockIdx.x * blockDim.x + threadIdx.x;
    if (idx >= n) return;
    const float px = pos[3 * idx + 0], py = pos[3 * idx + 1], pz = pos[3 * idx + 2];
    float y[64];
#pragma unroll
    for (int j = 0; j < 64; ++j) y[j] = bd1[j];
#pragma unroll
    for (int l = 0; l < LEVELS; ++l) {
        const float resf = (float)(16 << l);
        const float tx = px * resf, ty = py * resf, tz = pz * resf;
        const float fx = floorf(tx), fy = floorf(ty), fz = floorf(tz);
        const float wx = tx - fx, wy = ty - fy, wz = tz - fz;
        const unsigned ix = (unsigned)(int)fx, iy = (unsigned)(int)fy, iz = (unsigned)(int)fz;
        const unsigned hy0 = iy * 2654435761u, hy1 = hy0 + 2654435761u;
        const unsigned hz0 = iz * 805459861u,  hz1 = hz0 + 805459861u;
        const unsigned ix1 = ix + 1u;
        const float2* tb = (const float2*)tables + (size_t)l * TBL;
        const float2 e000 = tb[(ix  ^ hy0 ^ hz0) & TMASK];
        const float2 e001 = tb[(ix  ^ hy0 ^ hz1) & TMASK];
        const float2 e010 = tb[(ix  ^ hy1 ^ hz0) & TMASK];
        const float2 e011 = tb[(ix  ^ hy1 ^ hz1) & TMASK];
        const float2 e100 = tb[(ix1 ^ hy0 ^ hz0) & TMASK];
        const float2 e101 = tb[(ix1 ^ hy0 ^ hz1) & TMASK];
        const float2 e110 = tb[(ix1 ^ hy1 ^ hz0) & TMASK];
        const float2 e111 = tb[(ix1 ^ hy1 ^ hz1) & TMASK];
        const float ux = 1.f - wx, uy = 1.f - wy, uz = 1.f - wz;
        const float c000 = ux*uy*uz, c001 = ux*uy*wz, c010 = ux*wy*uz, c011 = ux*wy*wz;
        const float c100 = wx*uy*uz, c101 = wx*uy*wz, c110 = wx*wy*uz, c111 = wx*wy*wz;
        float f0 = e000.x*c000, f1 = e000.y*c000;
        f0 = fmaf(e001.x,c001,f0); f1 = fmaf(e001.y,c001,f1);
        f0 = fmaf(e010.x,c010,f0); f1 = fmaf(e010.y,c010,f1);
        f0 = fmaf(e011.x,c011,f0); f1 = fmaf(e011.y,c011,f1);
        f0 = fmaf(e100.x,c100,f0); f1 = fmaf(e100.y,c100,f1);
        f0 = fmaf(e101.x,c101,f0); f1 = fmaf(e101.y,c101,f1);
        f0 = fmaf(e110.x,c110,f0); f1 = fmaf(e110.y,c110,f1);
        f0 = fmaf(e111.x,c111,f0); f1 = fmaf(e111.y,c111,f1);
        const float* w0 = Wd1 + (size_t)(2 * l) * 64;
#pragma unroll
        for (int j = 0; j < 64; ++j)
            y[j] = fmaf(f0, w0[j], fmaf(f1, w0[64 + j], y[j]));
    }
    float d[16];
#pragma unroll
    for (int k = 0; k < 16; ++k) d[k] = bd2[k];
#pragma unroll
    for (int j = 0; j < 64; ++j) {
        const float a = fmaxf(y[j], 0.f);
#pragma unroll
        for (int k = 0; k < 16; ++k) d[k] = fmaf(a, Wd2[j * 16 + k], d[k]);
    }
    out[3 * n + idx] = fmaxf(d[15], 0.f);
    const float dx = dirp[3*idx], dy = dirp[3*idx+1], dz = dirp[3*idx+2];
    float sh[25];
    SH_BLOCK(sh, dx, dy, dz)
    float h1[64];
#pragma unroll
    for (int j = 0; j < 64; ++j) h1[j] = bc1[j];
#pragma unroll
    for (int i = 0; i < 16; ++i) {
#pragma unroll
        for (int j = 0; j < 64; ++j) h1[j] = fmaf(d[i], Wc1[i * 64 + j], h1[j]);
    }
#pragma unroll
    for (int s = 0; s < 25; ++s) {
#pragma unroll
        for (int j = 0; j < 64; ++j) h1[j] = fmaf(sh[s], Wc1[(16 + s) * 64 + j], h1[j]);
    }
    float h2[64];
#pragma unroll
    for (int j = 0; j < 64; ++j) h2[j] = bc2[j];
#pragma unroll
    for (int i = 0; i < 64; ++i) {
        const float a = fmaxf(h1[i], 0.f);
#pragma unroll
        for (int j = 0; j < 64; ++j) h2[j] = fmaf(a, Wc2[i * 64 + j], h2[j]);
    }
    float r0 = bc3[0], r1 = bc3[1], r2 = bc3[2];
#pragma unroll
    for (int j = 0; j < 64; ++j) {
        const float a = fmaxf(h2[j], 0.f);
        r0 = fmaf(a, Wc3[j * 3 + 0], r0);
        r1 = fmaf(a, Wc3[j * 3 + 1], r1);
        r2 = fmaf(a, Wc3[j * 3 + 2], r2);
    }
    out[3 * idx + 0] = 1.f / (1.f + expf(-r0));
    out[3 * idx + 1] = 1.f / (1.f + expf(-r1));
    out[3 * idx + 2] = 1.f / (1.f + expf(-r2));
}

extern "C" void kernel_launch(void* const* d_in, const int* in_sizes, int n_in,
                              void* d_out, int out_size, void* d_ws, size_t ws_size,
                              hipStream_t stream) {
    const float* pos    = (const float*)d_in[0];
    const float* dir    = (const float*)d_in[1];
    const float* tables = (const float*)d_in[2];
    const float* Wd1 = (const float*)d_in[3];
    const float* bd1 = (const float*)d_in[4];
    const float* Wd2 = (const float*)d_in[5];
    const float* bd2 = (const float*)d_in[6];
    const float* Wc1 = (const float*)d_in[7];
    const float* bc1 = (const float*)d_in[8];
    const float* Wc2 = (const float*)d_in[9];
    const float* bc2 = (const float*)d_in[10];
    const float* Wc3 = (const float*)d_in[11];
    const float* bc3 = (const float*)d_in[12];

    const int n = in_sizes[0] / 3;
    const int blocks = (n + 255) / 256;

    // workspace layout: [0, n*64) packed-bf16 feature planes;
    //                   [n*64, n*128) packed-bf16 tables (16*TBL uints)
    if (ws_size >= (size_t)n * 128 && n == 524288) {
        unsigned int* wsp  = (unsigned int*)d_ws;
        unsigned int* tb16 = (unsigned int*)((char*)d_ws + (size_t)n * 64);
        const int total = LEVELS * TBL;
        cvt_tables<<<total / 1024, 256, 0, stream>>>(tables, tb16, total);
        ngp_encode_lvl<<<16 * blocks, 256, 0, stream>>>(pos, tb16, wsp, n);
        ngp_mlp_mfma4<<<n / (128 * GROUPS), MT, 0, stream>>>((const unsigned int*)wsp, dir,
                                                             Wd1, bd1, Wd2, bd2,
                                                             Wc1, bc1, Wc2, bc2, Wc3, bc3,
                                                             (float*)d_out, n);
    } else {
        nerf_fused<<<blocks, 256, 0, stream>>>(pos, dir, tables,
                                               Wd1, bd1, Wd2, bd2,
                                               Wc1, bc1, Wc2, bc2, Wc3, bc3,
                                               (float*)d_out, n);
    }
}

// Round 5
// 360.445 us; speedup vs baseline: 1.3801x; 1.0008x over previous
//
#include <hip/hip_runtime.h>
#include <math.h>

#define LEVELS 16
#define TBL 524288          // 2^19 entries per level
#define TMASK (TBL - 1)

typedef short bf16x8 __attribute__((ext_vector_type(8)));
typedef float f32x4  __attribute__((ext_vector_type(4)));
typedef float fvec4  __attribute__((ext_vector_type(4)));
typedef unsigned int uvec4 __attribute__((ext_vector_type(4)));

static __device__ __forceinline__ unsigned short f2bf(float x) {
    unsigned u = __float_as_uint(x);
    u += 0x7fffu + ((u >> 16) & 1u);    // RNE
    return (unsigned short)(u >> 16);
}
static __device__ __forceinline__ float b2f(unsigned short h) {
    return __uint_as_float(((unsigned)h) << 16);
}

// SH degree-4 block, constants computed exactly as round-1 (verified correct).
#define SH_BLOCK(sh, dx, dy, dz)                                                          \
    const float x2 = dx * dx, y2 = dy * dy, z2 = dz * dz;                                 \
    const float xy = dx * dy, xz = dx * dz, yz = dy * dz;                                 \
    const float x4 = x2 * x2, y4 = y2 * y2;                                               \
    const float c0  = (float)(0.5 * sqrt(1.0 / M_PI));                                    \
    const float c1  = (float)(0.5 * sqrt(3.0 / M_PI));                                    \
    const float sub = (float)(0.25 * sqrt(5.0 / M_PI));                                   \
    const float v1  = (float)(0.25 * sqrt(15.0 / M_PI));                                  \
    const float v2  = (float)(0.5 * sqrt(15.0 / M_PI));                                   \
    const float v3  = (float)(0.75 * sqrt(5.0 / M_PI));                                   \
    const float w1c = (float)(0.25 * sqrt(105.0 / M_PI));                                 \
    const float w2c = (float)(0.5 * sqrt(105.0 / M_PI));                                  \
    const float w3c = (float)(0.25 * sqrt(35.0 / (2.0 * M_PI)));                          \
    const float w4c = (float)(0.5 * sqrt(7.0 / (6.0 * M_PI)));                            \
    sh[0] = c0;                                                                           \
    sh[1] = -c1 * dy;                                                                     \
    sh[2] =  c1 * dz;                                                                     \
    sh[3] = -c1 * dx;                                                                     \
    sh[4] =  v2 * xy;                                                                     \
    sh[5] = -v2 * yz;                                                                     \
    sh[6] =  v3 * z2 - sub;                                                               \
    sh[7] = -v2 * xz;                                                                     \
    sh[8] =  v1 * x2 - v1 * y2;                                                           \
    sh[9]  = -w3c * dy * (3.0f * x2 - y2);                                                \
    sh[10] =  w2c * xy * dz;                                                              \
    sh[11] =  w4c * dy * (1.5f - 7.5f * z2);                                              \
    sh[12] =  1.24392110863372f * dz * (1.5f * z2 - 0.5f) - 0.497568443453487f * dz;      \
    sh[13] =  w4c * dx * (1.5f - 7.5f * z2);                                              \
    sh[14] =  w1c * dz * (x2 - y2);                                                       \
    sh[15] = -w3c * dx * (x2 - 3.0f * y2);                                                \
    sh[16] =  2.5033429417967f * xy * (x2 - y2);                                          \
    sh[17] = -1.77013076977993f * yz * (3.0f * x2 - y2);                                  \
    sh[18] =  0.126156626101008f * xy * (52.5f * z2 - 7.5f);                              \
    sh[19] =  0.267618617422916f * dy * (2.33333333333333f * dz * (1.5f - 7.5f * z2) + 4.0f * dz); \
    sh[20] =  1.48099765681286f * dz * (1.66666666666667f * dz * (1.5f * z2 - 0.5f) - 0.666666666666667f * dz) \
              - 0.952069922236839f * z2 + 0.317356640745613f;                             \
    sh[21] =  0.267618617422916f * dx * (2.33333333333333f * dz * (1.5f - 7.5f * z2) + 4.0f * dz); \
    sh[22] =  0.063078313050504f * (x2 - y2) * (52.5f * z2 - 7.5f);                       \
    sh[23] = -1.77013076977993f * xz * (x2 - 3.0f * y2);                                  \
    sh[24] = -3.75501441269506f * x2 * y2 + 0.625835735449176f * x4 + 0.625835735449176f * y4;

// ------------------------------------------------------------------
// Kernel 0: pack fp32 tables -> bf16x2 (one uint per entry).
// ------------------------------------------------------------------
__global__ __launch_bounds__(256)
void cvt_tables(const float* __restrict__ tables,
                unsigned int* __restrict__ tb16, int total)
{
    const int i = (blockIdx.x * 256 + threadIdx.x) * 4;   // 4 entries/thread
    if (i >= total) return;
    const fvec4 a = __builtin_nontemporal_load((const fvec4*)(tables + 2 * (size_t)i));
    const fvec4 b = __builtin_nontemporal_load((const fvec4*)(tables + 2 * (size_t)i) + 1);
    uvec4 o;
    o.x = ((unsigned)f2bf(a.y) << 16) | f2bf(a.x);
    o.y = ((unsigned)f2bf(a.w) << 16) | f2bf(a.z);
    o.z = ((unsigned)f2bf(b.y) << 16) | f2bf(b.x);
    o.w = ((unsigned)f2bf(b.w) << 16) | f2bf(b.z);
    __builtin_nontemporal_store(o, (uvec4*)&tb16[i]);
}

// ------------------------------------------------------------------
// Kernel 1: hash-grid gather, level<->XCD affinity.
// R15: TWO points per thread (idx, idx+256). Encode is latency-bound
// (R4: VALUBusy 15.9%, HBM 7.9%, occ 81% -> waves parked on vmcnt).
// Both points' hashes are computed up front so the compiler batches
// 8-16 independent gathers per thread before the first wait -> ~2x
// memory-level parallelism. 512 pts/block, grid 16384, same XCD map.
// ------------------------------------------------------------------
__global__ __launch_bounds__(256)
void ngp_encode_lvl(const float* __restrict__ pos,
                    const unsigned int* __restrict__ tb16,
                    unsigned int* __restrict__ wsp, int n)
{
    const int b = blockIdx.x;
    const int p = b & 7;
    const int h = b >> 13;                 // 8192 blocks per half (n = 2^19)
    const int l = 2 * p + h;
    const int c = (b & 8191) >> 3;
    const int base = c * 512 + threadIdx.x;
    if (l >= LEVELS || base + 256 >= n) return;

    const unsigned int* tb = tb16 + (size_t)l * TBL;
    const float resf = (float)(16 << l);

    float f0r[2], f1r[2];
#pragma unroll
    for (int s = 0; s < 2; ++s) {
        const int idx = base + s * 256;
        const float px = pos[3 * idx + 0];
        const float py = pos[3 * idx + 1];
        const float pz = pos[3 * idx + 2];

        const float tx = px * resf, ty = py * resf, tz = pz * resf;
        const float fx = floorf(tx), fy = floorf(ty), fz = floorf(tz);
        const float wx = tx - fx, wy = ty - fy, wz = tz - fz;
        const unsigned ix = (unsigned)(int)fx;
        const unsigned iy = (unsigned)(int)fy;
        const unsigned iz = (unsigned)(int)fz;
        const unsigned hy0 = iy * 2654435761u, hy1 = hy0 + 2654435761u;
        const unsigned hz0 = iz * 805459861u,  hz1 = hz0 + 805459861u;
        const unsigned ix1 = ix + 1u;

        const unsigned hA = hy0 ^ hz0;
        const unsigned hB = hy0 ^ hz1;
        const unsigned hC = hy1 ^ hz0;
        const unsigned hD = hy1 ^ hz1;

        unsigned eA0, eA1, eB0, eB1, eC0, eC1, eD0, eD1;
        if ((ix & 1u) == 0u) {
            // even ix: {ix^h, (ix+1)^h} = {m, m^1} -> one aligned 8B load
            const uint2 pA = *(const uint2*)&tb[((ix ^ hA) & TMASK) & ~1u];
            const uint2 pB = *(const uint2*)&tb[((ix ^ hB) & TMASK) & ~1u];
            const uint2 pC = *(const uint2*)&tb[((ix ^ hC) & TMASK) & ~1u];
            const uint2 pD = *(const uint2*)&tb[((ix ^ hD) & TMASK) & ~1u];
            const unsigned sA = hA & 1u, sB = hB & 1u, sC = hC & 1u, sD = hD & 1u;
            eA0 = sA ? pA.y : pA.x;  eA1 = sA ? pA.x : pA.y;
            eB0 = sB ? pB.y : pB.x;  eB1 = sB ? pB.x : pB.y;
            eC0 = sC ? pC.y : pC.x;  eC1 = sC ? pC.x : pC.y;
            eD0 = sD ? pD.y : pD.x;  eD1 = sD ? pD.x : pD.y;
        } else {
            eA0 = tb[(ix  ^ hA) & TMASK];  eA1 = tb[(ix1 ^ hA) & TMASK];
            eB0 = tb[(ix  ^ hB) & TMASK];  eB1 = tb[(ix1 ^ hB) & TMASK];
            eC0 = tb[(ix  ^ hC) & TMASK];  eC1 = tb[(ix1 ^ hC) & TMASK];
            eD0 = tb[(ix  ^ hD) & TMASK];  eD1 = tb[(ix1 ^ hD) & TMASK];
        }

#define UNPX(e) __uint_as_float((e) << 16)
#define UNPY(e) __uint_as_float((e) & 0xffff0000u)

        const float ux = 1.f - wx, uy = 1.f - wy, uz = 1.f - wz;
        const float c000 = ux * uy * uz, c001 = ux * uy * wz;
        const float c010 = ux * wy * uz, c011 = ux * wy * wz;
        const float c100 = wx * uy * uz, c101 = wx * uy * wz;
        const float c110 = wx * wy * uz, c111 = wx * wy * wz;

        float f0 = UNPX(eA0) * c000, f1 = UNPY(eA0) * c000;
        f0 = fmaf(UNPX(eB0), c001, f0); f1 = fmaf(UNPY(eB0), c001, f1);
        f0 = fmaf(UNPX(eC0), c010, f0); f1 = fmaf(UNPY(eC0), c010, f1);
        f0 = fmaf(UNPX(eD0), c011, f0); f1 = fmaf(UNPY(eD0), c011, f1);
        f0 = fmaf(UNPX(eA1), c100, f0); f1 = fmaf(UNPY(eA1), c100, f1);
        f0 = fmaf(UNPX(eB1), c101, f0); f1 = fmaf(UNPY(eB1), c101, f1);
        f0 = fmaf(UNPX(eC1), c110, f0); f1 = fmaf(UNPY(eC1), c110, f1);
        f0 = fmaf(UNPX(eD1), c111, f0); f1 = fmaf(UNPY(eD1), c111, f1);
        f0r[s] = f0;
        f1r[s] = f1;
    }

#pragma unroll
    for (int s = 0; s < 2; ++s) {
        const unsigned int h0 = f2bf(f0r[s]);
        const unsigned int h1 = f2bf(f1r[s]);
        __builtin_nontemporal_store((h1 << 16) | h0,
                                    &wsp[(size_t)l * n + base + s * 256]);
    }
}

// ------------------------------------------------------------------
// Kernel 2: split-precision MFMA MLP, persistent blocks (unchanged R14:
// __launch_bounds__(512,2) -> no spill; SPLIT_TILE staged B-tiles).
// ------------------------------------------------------------------
#define MT   512
#define GROUPS 8
#define SW1  32                  // Wd1 k-stride (shorts), rows 16B-aligned
#define SW   72                  // 64-k weight stride (shorts), rows 16B-aligned
#define SA   65                  // act k-stride (floats)
#define OW1  0                   // 64*32 = 2048
#define OW2  2048                // 16*72 = 1152
#define OC1H 3200                // 64*72 = 4608
#define OC1L 7808
#define OC2H 12416
#define OC2L 17024
#define OC3H 21632               // 16*72 = 1152
#define OC3L 22784
#define WTOT 23936               // shorts = 47,872 B; + act 33,280 B = 81,152 B

__global__ __launch_bounds__(512, 2)
void ngp_mlp_mfma4(const unsigned int* __restrict__ wsp,
                   const float* __restrict__ dirp,
                   const float* __restrict__ Wd1, const float* __restrict__ bd1,
                   const float* __restrict__ Wd2, const float* __restrict__ bd2,
                   const float* __restrict__ Wc1, const float* __restrict__ bc1,
                   const float* __restrict__ Wc2, const float* __restrict__ bc2,
                   const float* __restrict__ Wc3, const float* __restrict__ bc3,
                   float* __restrict__ out, int n)
{
    __shared__ short wsm[WTOT];
    __shared__ float act[8 * 16 * SA];
    const int tid = threadIdx.x;

    for (int t = tid; t < WTOT; t += MT) wsm[t] = 0;
    __syncthreads();

    for (int g = tid; g < 32 * 64; g += MT) {            // Wd1 (32,64) single
        const int k = g >> 6, nn = g & 63;
        wsm[OW1 + nn * SW1 + k] = f2bf(Wd1[g]);
    }
    for (int g = tid; g < 64 * 16; g += MT) {            // Wd2 (64,16) single
        const int k = g >> 4, nn = g & 15;
        wsm[OW2 + nn * SW + k] = f2bf(Wd2[g]);
    }
    for (int g = tid; g < 41 * 64; g += MT) {            // Wc1 (41,64) hi+lo
        const int k = g >> 6, nn = g & 63;
        const float w = Wc1[g];
        const unsigned short hh = f2bf(w);
        wsm[OC1H + nn * SW + k] = hh;
        wsm[OC1L + nn * SW + k] = f2bf(w - b2f(hh));
    }
    for (int g = tid; g < 64 * 64; g += MT) {            // Wc2 (64,64) hi+lo
        const int k = g >> 6, nn = g & 63;
        const float w = Wc2[g];
        const unsigned short hh = f2bf(w);
        wsm[OC2H + nn * SW + k] = hh;
        wsm[OC2L + nn * SW + k] = f2bf(w - b2f(hh));
    }
    for (int g = tid; g < 64 * 3; g += MT) {             // Wc3 (64,3) hi+lo
        const int k = g / 3, nn = g - 3 * k;
        const float w = Wc3[g];
        const unsigned short hh = f2bf(w);
        wsm[OC3H + nn * SW + k] = hh;
        wsm[OC3L + nn * SW + k] = f2bf(w - b2f(hh));
    }
    __syncthreads();

    const int wid = tid >> 6;              // 0..7
    const int lane = tid & 63;
    const int ln = lane & 15;
    const int qd = lane >> 4;
    float* A = act + wid * (16 * SA);

    // biases hoisted to registers (loop-invariant)
    float bd1v[4], bc1v[4], bc2v[4];
#pragma unroll
    for (int t = 0; t < 4; ++t) {
        bd1v[t] = bd1[t * 16 + ln];
        bc1v[t] = bc1[t * 16 + ln];
        bc2v[t] = bc2[t * 16 + ln];
    }
    const float bd2v = bd2[ln];
    const float bc3v = (ln < 3) ? bc3[ln] : 0.f;

#define LOAD_SPLIT(ah, al, k0)                                   \
    {                                                            \
        _Pragma("unroll")                                        \
        for (int j = 0; j < 8; ++j) {                            \
            const float v = A[ln * SA + (k0) + j];               \
            const unsigned short hb = f2bf(v);                   \
            ah[j] = (short)hb;                                   \
            al[j] = (short)f2bf(v - b2f(hb));                    \
        }                                                        \
    }

// hi-half B-tiles first, 4 MFMAs, then lo-half B-tiles, 2 MFMAs:
// same accumulation order as before (bit-identical), but only 2
// B-tiles (8 VGPR) live at any point instead of 4 (16).
#define SPLIT_TILE(acc, ah0, ah1, al0, al1, OH, OL, row)                                          \
    {                                                                                             \
        const bf16x8 bh0 = *(const bf16x8*)&wsm[(OH) + (row) * SW + qd * 8];                      \
        const bf16x8 bh1 = *(const bf16x8*)&wsm[(OH) + (row) * SW + 32 + qd * 8];                 \
        acc = __builtin_amdgcn_mfma_f32_16x16x32_bf16(ah0, bh0, acc, 0, 0, 0);                    \
        acc = __builtin_amdgcn_mfma_f32_16x16x32_bf16(ah1, bh1, acc, 0, 0, 0);                    \
        acc = __builtin_amdgcn_mfma_f32_16x16x32_bf16(al0, bh0, acc, 0, 0, 0);                    \
        acc = __builtin_amdgcn_mfma_f32_16x16x32_bf16(al1, bh1, acc, 0, 0, 0);                    \
        const bf16x8 bl0 = *(const bf16x8*)&wsm[(OL) + (row) * SW + qd * 8];                      \
        const bf16x8 bl1 = *(const bf16x8*)&wsm[(OL) + (row) * SW + 32 + qd * 8];                 \
        acc = __builtin_amdgcn_mfma_f32_16x16x32_bf16(ah0, bl0, acc, 0, 0, 0);                    \
        acc = __builtin_amdgcn_mfma_f32_16x16x32_bf16(ah1, bl1, acc, 0, 0, 0);                    \
    }

    // ---- register prefetch of group 0's globals (packed bf16 planes) ----
    const int pt0 = blockIdx.x * (GROUPS * 128) + wid * 16 + ln;
    unsigned int xu0, xu1, xu2, xu3;
    float dq0, dq1, dq2;
    xu0 = wsp[(size_t)(qd * 4 + 0) * n + pt0];
    xu1 = wsp[(size_t)(qd * 4 + 1) * n + pt0];
    xu2 = wsp[(size_t)(qd * 4 + 2) * n + pt0];
    xu3 = wsp[(size_t)(qd * 4 + 3) * n + pt0];
    dq0 = dirp[3 * pt0 + 0];
    dq1 = dirp[3 * pt0 + 1];
    dq2 = dirp[3 * pt0 + 2];

#pragma unroll 1
    for (int grp = 0; grp < GROUPS; ++grp) {
        const int pt_base = blockIdx.x * (GROUPS * 128) + grp * 128 + wid * 16;
        const int pt = pt_base + ln;

        // consume prefetched globals (already bf16 bits — no converts)
        bf16x8 ax;
        ax[0] = (short)(xu0 & 0xffffu); ax[1] = (short)(xu0 >> 16);
        ax[2] = (short)(xu1 & 0xffffu); ax[3] = (short)(xu1 >> 16);
        ax[4] = (short)(xu2 & 0xffffu); ax[5] = (short)(xu2 >> 16);
        ax[6] = (short)(xu3 & 0xffffu); ax[7] = (short)(xu3 >> 16);
        const float ddx = dq0, ddy = dq1, ddz = dq2;

        // issue next group's globals now (consumed next iteration)
        if (grp + 1 < GROUPS) {
            const int ptn = pt + 128;
            xu0 = wsp[(size_t)(qd * 4 + 0) * n + ptn];
            xu1 = wsp[(size_t)(qd * 4 + 1) * n + ptn];
            xu2 = wsp[(size_t)(qd * 4 + 2) * n + ptn];
            xu3 = wsp[(size_t)(qd * 4 + 3) * n + ptn];
            dq0 = dirp[3 * ptn + 0];
            dq1 = dirp[3 * ptn + 1];
            dq2 = dirp[3 * ptn + 2];
        }

        // ---- d1: Y[16x64] = X @ Wd1 (single bf16) ----
        f32x4 yacc[4];
#pragma unroll
        for (int t = 0; t < 4; ++t) {
            const bf16x8 b = *(const bf16x8*)&wsm[OW1 + (t * 16 + ln) * SW1 + qd * 8];
            const float bv = bd1v[t];
            f32x4 acc = {bv, bv, bv, bv};
            yacc[t] = __builtin_amdgcn_mfma_f32_16x16x32_bf16(ax, b, acc, 0, 0, 0);
        }
#pragma unroll
        for (int t = 0; t < 4; ++t)
#pragma unroll
            for (int r = 0; r < 4; ++r)
                A[(qd * 4 + r) * SA + t * 16 + ln] = fmaxf(yacc[t][r], 0.f);   // fp32

        // ---- d2: D[16x16] = relu(Y) @ Wd2 (single bf16) ----
        {
            bf16x8 a0, a1;
#pragma unroll
            for (int j = 0; j < 8; ++j) a0[j] = (short)f2bf(A[ln * SA + qd * 8 + j]);
#pragma unroll
            for (int j = 0; j < 8; ++j) a1[j] = (short)f2bf(A[ln * SA + 32 + qd * 8 + j]);
            const bf16x8 b0 = *(const bf16x8*)&wsm[OW2 + ln * SW + qd * 8];
            const bf16x8 b1 = *(const bf16x8*)&wsm[OW2 + ln * SW + 32 + qd * 8];
            const float bv = bd2v;
            f32x4 acc = {bv, bv, bv, bv};
            acc = __builtin_amdgcn_mfma_f32_16x16x32_bf16(a0, b0, acc, 0, 0, 0);
            acc = __builtin_amdgcn_mfma_f32_16x16x32_bf16(a1, b1, acc, 0, 0, 0);
            if (ln == 15) {
#pragma unroll
                for (int r = 0; r < 4; ++r)
                    out[3 * n + pt_base + qd * 4 + r] = fmaxf(acc[r], 0.f);    // sigma
            }
#pragma unroll
            for (int r = 0; r < 4; ++r)
                A[(qd * 4 + r) * SA + ln] = acc[r];        // raw D fp32, k=0..15
        }

        // ---- SH -> act fp32, k=16..40 (k=41..63 stale, Wc1 rows zeroed) ----
        // Fully unrolled + predicated: sh[] static-indexed -> stays in VGPRs.
        {
            float sh[25];
            SH_BLOCK(sh, ddx, ddy, ddz)
#pragma unroll
            for (int i = 0; i < 25; ++i)
                if ((i & 3) == qd)
                    A[ln * SA + 16 + i] = sh[i];
        }

        // ---- c1: H1 = [D|SH|0] @ Wc1 (split) ----
        {
            bf16x8 ah0, ah1, al0, al1;
            LOAD_SPLIT(ah0, al0, qd * 8)
            LOAD_SPLIT(ah1, al1, 32 + qd * 8)
            f32x4 hacc[4];
#pragma unroll
            for (int t = 0; t < 4; ++t) {
                const float bv = bc1v[t];
                f32x4 acc = {bv, bv, bv, bv};
                SPLIT_TILE(acc, ah0, ah1, al0, al1, OC1H, OC1L, t * 16 + ln)
                hacc[t] = acc;
            }
#pragma unroll
            for (int t = 0; t < 4; ++t)
#pragma unroll
                for (int r = 0; r < 4; ++r)
                    A[(qd * 4 + r) * SA + t * 16 + ln] = fmaxf(hacc[t][r], 0.f);
        }

        // ---- c2: H2 = relu(H1) @ Wc2 (split) ----
        {
            bf16x8 ah0, ah1, al0, al1;
            LOAD_SPLIT(ah0, al0, qd * 8)
            LOAD_SPLIT(ah1, al1, 32 + qd * 8)
            f32x4 hacc[4];
#pragma unroll
            for (int t = 0; t < 4; ++t) {
                const float bv = bc2v[t];
                f32x4 acc = {bv, bv, bv, bv};
                SPLIT_TILE(acc, ah0, ah1, al0, al1, OC2H, OC2L, t * 16 + ln)
                hacc[t] = acc;
            }
#pragma unroll
            for (int t = 0; t < 4; ++t)
#pragma unroll
                for (int r = 0; r < 4; ++r)
                    A[(qd * 4 + r) * SA + t * 16 + ln] = fmaxf(hacc[t][r], 0.f);
        }

        // ---- c3 + sigmoid: R = relu(H2) @ Wc3 (split) ----
        {
            bf16x8 ah0, ah1, al0, al1;
            LOAD_SPLIT(ah0, al0, qd * 8)
            LOAD_SPLIT(ah1, al1, 32 + qd * 8)
            const float bv = bc3v;
            f32x4 acc = {bv, bv, bv, bv};
            SPLIT_TILE(acc, ah0, ah1, al0, al1, OC3H, OC3L, ln)
            if (ln < 3) {
#pragma unroll
                for (int r = 0; r < 4; ++r)
                    out[3 * (pt_base + qd * 4 + r) + ln] = 1.f / (1.f + expf(-acc[r]));
            }
        }
    }
}

// ------------------------------------------------------------------
// Fallback: round-1 fused kernel (if ws too small / n not 2^19) — proven
// ------------------------------------------------------------------
__global__ __launch_bounds__(256)
void nerf_fused(const float* __restrict__ pos,
                const float* __restrict__ dirp,
                const float* __restrict__ tables,
                const float* __restrict__ Wd1, const float* __restrict__ bd1,
                const float* __restrict__ Wd2, const float* __restrict__ bd2,
                const float* __restrict__ Wc1, const float* __restrict__ bc1,
                const float* __restrict__ Wc2, const float* __restrict__ bc2,
                const float* __restrict__ Wc3, const float* __restrict__ bc3,
                float* __restrict__ out, int n)
{
    const int idx = blockIdx.x * blockDim.x + threadIdx.x;
    if (idx >= n) return;
    const float px = pos[3 * idx + 0], py = pos[3 * idx + 1], pz = pos[3 * idx + 2];
    float y[64];
#pragma unroll
    for (int j = 0; j < 64; ++j) y[j] = bd1[j];
#pragma unroll
    for (int l = 0; l < LEVELS; ++l) {
        const float resf = (float)(16 << l);
        const float tx = px * resf, ty = py * resf, tz = pz * resf;
        const float fx = floorf(tx), fy = floorf(ty), fz = floorf(tz);
        const float wx = tx - fx, wy = ty - fy, wz = tz - fz;
        const unsigned ix = (unsigned)(int)fx, iy = (unsigned)(int)fy, iz = (unsigned)(int)fz;
        const unsigned hy0 = iy * 2654435761u, hy1 = hy0 + 2654435761u;
        const unsigned hz0 = iz * 805459861u,  hz1 = hz0 + 805459861u;
        const unsigned ix1 = ix + 1u;
        const float2* tb = (const float2*)tables + (size_t)l * TBL;
        const float2 e000 = tb[(ix  ^ hy0 ^ hz0) & TMASK];
        const float2 e001 = tb[(ix  ^ hy0 ^ hz1) & TMASK];
        const float2 e010 = tb[(ix  ^ hy1 ^ hz0) & TMASK];
        const float2 e011 = tb[(ix  ^ hy1 ^ hz1) & TMASK];
        const float2 e100 = tb[(ix1 ^ hy0 ^ hz0) & TMASK];
        const float2 e101 = tb[(ix1 ^ hy0 ^ hz1) & TMASK];
        const float2 e110 = tb[(ix1 ^ hy1 ^ hz0) & TMASK];
        const float2 e111 = tb[(ix1 ^ hy1 ^ hz1) & TMASK];
        const float ux = 1.f - wx, uy = 1.f - wy, uz = 1.f - wz;
        const float c000 = ux*uy*uz, c001 = ux*uy*wz, c010 = ux*wy*uz, c011 = ux*wy*wz;
        const float c100 = wx*uy*uz, c101 = wx*uy*wz, c110 = wx*wy*uz, c111 = wx*wy*wz;
        float f0 = e000.x*c000, f1 = e000.y*c000;
        f0 = fmaf(e001.x,c001,f0); f1 = fmaf(e001.y,c001,f1);
        f0 = fmaf(e010.x,c010,f0); f1 = fmaf(e010.y,c010,f1);
        f0 = fmaf(e011.x,c011,f0); f1 = fmaf(e011.y,c011,f1);
        f0 = fmaf(e100.x,c100,f0); f1 = fmaf(e100.y,c100,f1);
        f0 = fmaf(e101.x,c101,f0); f1 = fmaf(e101.y,c101,f1);
        f0 = fmaf(e110.x,c110,f0); f1 = fmaf(e110.y,c110,f1);
        f0 = fmaf(e111.x,c111,f0); f1 = fmaf(e111.y,c111,f1);
        const float* w0 = Wd1 + (size_t)(2 * l) * 64;
#pragma unroll
        for (int j = 0; j < 64; ++j)
            y[j] = fmaf(f0, w0[j], fmaf(f1, w0[64 + j], y[j]));
    }
    float d[16];
#pragma unroll
    for (int k = 0; k < 16; ++k) d[k] = bd2[k];
#pragma unroll
    for (int j = 0; j < 64; ++j) {
        const float a = fmaxf(y[j], 0.f);
#pragma unroll
        for (int k = 0; k < 16; ++k) d[k] = fmaf(a, Wd2[j * 16 + k], d[k]);
    }
    out[3 * n + idx] = fmaxf(d[15], 0.f);
    const float dx = dirp[3*idx], dy = dirp[3*idx+1], dz = dirp[3*idx+2];
    float sh[25];
    SH_BLOCK(sh, dx, dy, dz)
    float h1[64];
#pragma unroll
    for (int j = 0; j < 64; ++j) h1[j] = bc1[j];
#pragma unroll
    for (int i = 0; i < 16; ++i) {
#pragma unroll
        for (int j = 0; j < 64; ++j) h1[j] = fmaf(d[i], Wc1[i * 64 + j], h1[j]);
    }
#pragma unroll
    for (int s = 0; s < 25; ++s) {
#pragma unroll
        for (int j = 0; j < 64; ++j) h1[j] = fmaf(sh[s], Wc1[(16 + s) * 64 + j], h1[j]);
    }
    float h2[64];
#pragma unroll
    for (int j = 0; j < 64; ++j) h2[j] = bc2[j];
#pragma unroll
    for (int i = 0; i < 64; ++i) {
        const float a = fmaxf(h1[i], 0.f);
#pragma unroll
        for (int j = 0; j < 64; ++j) h2[j] = fmaf(a, Wc2[i * 64 + j], h2[j]);
    }
    float r0 = bc3[0], r1 = bc3[1], r2 = bc3[2];
#pragma unroll
    for (int j = 0; j < 64; ++j) {
        const float a = fmaxf(h2[j], 0.f);
        r0 = fmaf(a, Wc3[j * 3 + 0], r0);
        r1 = fmaf(a, Wc3[j * 3 + 1], r1);
        r2 = fmaf(a, Wc3[j * 3 + 2], r2);
    }
    out[3 * idx + 0] = 1.f / (1.f + expf(-r0));
    out[3 * idx + 1] = 1.f / (1.f + expf(-r1));
    out[3 * idx + 2] = 1.f / (1.f + expf(-r2));
}

extern "C" void kernel_launch(void* const* d_in, const int* in_sizes, int n_in,
                              void* d_out, int out_size, void* d_ws, size_t ws_size,
                              hipStream_t stream) {
    const float* pos    = (const float*)d_in[0];
    const float* dir    = (const float*)d_in[1];
    const float* tables = (const float*)d_in[2];
    const float* Wd1 = (const float*)d_in[3];
    const float* bd1 = (const float*)d_in[4];
    const float* Wd2 = (const float*)d_in[5];
    const float* bd2 = (const float*)d_in[6];
    const float* Wc1 = (const float*)d_in[7];
    const float* bc1 = (const float*)d_in[8];
    const float* Wc2 = (const float*)d_in[9];
    const float* bc2 = (const float*)d_in[10];
    const float* Wc3 = (const float*)d_in[11];
    const float* bc3 = (const float*)d_in[12];

    const int n = in_sizes[0] / 3;
    const int blocks = (n + 255) / 256;

    // workspace layout: [0, n*64) packed-bf16 feature planes;
    //                   [n*64, n*128) packed-bf16 tables (16*TBL uints)
    if (ws_size >= (size_t)n * 128 && n == 524288) {
        unsigned int* wsp  = (unsigned int*)d_ws;
        unsigned int* tb16 = (unsigned int*)((char*)d_ws + (size_t)n * 64);
        const int total = LEVELS * TBL;
        cvt_tables<<<total / 1024, 256, 0, stream>>>(tables, tb16, total);
        ngp_encode_lvl<<<16 * (n / 512), 256, 0, stream>>>(pos, tb16, wsp, n);
        ngp_mlp_mfma4<<<n / (128 * GROUPS), MT, 0, stream>>>((const unsigned int*)wsp, dir,
                                                             Wd1, bd1, Wd2, bd2,
                                                             Wc1, bc1, Wc2, bc2, Wc3, bc3,
                                                             (float*)d_out, n);
    } else {
        nerf_fused<<<blocks, 256, 0, stream>>>(pos, dir, tables,
                                               Wd1, bd1, Wd2, bd2,
                                               Wc1, bc1, Wc2, bc2, Wc3, bc3,
                                               (float*)d_out, n);
    }
}

// Round 6
// 359.148 us; speedup vs baseline: 1.3851x; 1.0036x over previous
//
#include <hip/hip_runtime.h>
#include <math.h>

#define LEVELS 16
#define TBL 524288          // 2^19 entries per level
#define TMASK (TBL - 1)

typedef short bf16x8 __attribute__((ext_vector_type(8)));
typedef float f32x4  __attribute__((ext_vector_type(4)));
typedef float fvec4  __attribute__((ext_vector_type(4)));
typedef unsigned int uvec4 __attribute__((ext_vector_type(4)));

static __device__ __forceinline__ unsigned short f2bf(float x) {
    unsigned u = __float_as_uint(x);
    u += 0x7fffu + ((u >> 16) & 1u);    // RNE
    return (unsigned short)(u >> 16);
}
static __device__ __forceinline__ float b2f(unsigned short h) {
    return __uint_as_float(((unsigned)h) << 16);
}

// SH degree-4 block, constants computed exactly as round-1 (verified correct).
#define SH_BLOCK(sh, dx, dy, dz)                                                          \
    const float x2 = dx * dx, y2 = dy * dy, z2 = dz * dz;                                 \
    const float xy = dx * dy, xz = dx * dz, yz = dy * dz;                                 \
    const float x4 = x2 * x2, y4 = y2 * y2;                                               \
    const float c0  = (float)(0.5 * sqrt(1.0 / M_PI));                                    \
    const float c1  = (float)(0.5 * sqrt(3.0 / M_PI));                                    \
    const float sub = (float)(0.25 * sqrt(5.0 / M_PI));                                   \
    const float v1  = (float)(0.25 * sqrt(15.0 / M_PI));                                  \
    const float v2  = (float)(0.5 * sqrt(15.0 / M_PI));                                   \
    const float v3  = (float)(0.75 * sqrt(5.0 / M_PI));                                   \
    const float w1c = (float)(0.25 * sqrt(105.0 / M_PI));                                 \
    const float w2c = (float)(0.5 * sqrt(105.0 / M_PI));                                  \
    const float w3c = (float)(0.25 * sqrt(35.0 / (2.0 * M_PI)));                          \
    const float w4c = (float)(0.5 * sqrt(7.0 / (6.0 * M_PI)));                            \
    sh[0] = c0;                                                                           \
    sh[1] = -c1 * dy;                                                                     \
    sh[2] =  c1 * dz;                                                                     \
    sh[3] = -c1 * dx;                                                                     \
    sh[4] =  v2 * xy;                                                                     \
    sh[5] = -v2 * yz;                                                                     \
    sh[6] =  v3 * z2 - sub;                                                               \
    sh[7] = -v2 * xz;                                                                     \
    sh[8] =  v1 * x2 - v1 * y2;                                                           \
    sh[9]  = -w3c * dy * (3.0f * x2 - y2);                                                \
    sh[10] =  w2c * xy * dz;                                                              \
    sh[11] =  w4c * dy * (1.5f - 7.5f * z2);                                              \
    sh[12] =  1.24392110863372f * dz * (1.5f * z2 - 0.5f) - 0.497568443453487f * dz;      \
    sh[13] =  w4c * dx * (1.5f - 7.5f * z2);                                              \
    sh[14] =  w1c * dz * (x2 - y2);                                                       \
    sh[15] = -w3c * dx * (x2 - 3.0f * y2);                                                \
    sh[16] =  2.5033429417967f * xy * (x2 - y2);                                          \
    sh[17] = -1.77013076977993f * yz * (3.0f * x2 - y2);                                  \
    sh[18] =  0.126156626101008f * xy * (52.5f * z2 - 7.5f);                              \
    sh[19] =  0.267618617422916f * dy * (2.33333333333333f * dz * (1.5f - 7.5f * z2) + 4.0f * dz); \
    sh[20] =  1.48099765681286f * dz * (1.66666666666667f * dz * (1.5f * z2 - 0.5f) - 0.666666666666667f * dz) \
              - 0.952069922236839f * z2 + 0.317356640745613f;                             \
    sh[21] =  0.267618617422916f * dx * (2.33333333333333f * dz * (1.5f - 7.5f * z2) + 4.0f * dz); \
    sh[22] =  0.063078313050504f * (x2 - y2) * (52.5f * z2 - 7.5f);                       \
    sh[23] = -1.77013076977993f * xz * (x2 - 3.0f * y2);                                  \
    sh[24] = -3.75501441269506f * x2 * y2 + 0.625835735449176f * x4 + 0.625835735449176f * y4;

// ------------------------------------------------------------------
// Kernel 0: pack fp32 tables -> bf16x2 (one uint per entry).
// ------------------------------------------------------------------
__global__ __launch_bounds__(256)
void cvt_tables(const float* __restrict__ tables,
                unsigned int* __restrict__ tb16, int total)
{
    const int i = (blockIdx.x * 256 + threadIdx.x) * 4;   // 4 entries/thread
    if (i >= total) return;
    const fvec4 a = __builtin_nontemporal_load((const fvec4*)(tables + 2 * (size_t)i));
    const fvec4 b = __builtin_nontemporal_load((const fvec4*)(tables + 2 * (size_t)i) + 1);
    uvec4 o;
    o.x = ((unsigned)f2bf(a.y) << 16) | f2bf(a.x);
    o.y = ((unsigned)f2bf(a.w) << 16) | f2bf(a.z);
    o.z = ((unsigned)f2bf(b.y) << 16) | f2bf(b.x);
    o.w = ((unsigned)f2bf(b.w) << 16) | f2bf(b.z);
    __builtin_nontemporal_store(o, (uvec4*)&tb16[i]);
}

// ------------------------------------------------------------------
// Kernel 1: hash-grid gather, level<->XCD affinity. R16 = R4 version
// (1 pt/thread): R5's 2-pt MLP was neutral (encode is L2-request-
// THROUGHPUT bound at ~16 req/cyc/XCD, ~164 us model vs 157 measured;
// not latency-bound). Request floor ~110 us (all-even-ix merge).
// ------------------------------------------------------------------
__global__ __launch_bounds__(256)
void ngp_encode_lvl(const float* __restrict__ pos,
                    const unsigned int* __restrict__ tb16,
                    unsigned int* __restrict__ wsp, int n)
{
    const int b = blockIdx.x;
    const int p = b & 7;
    const int h = b >> 14;                 // 16384 blocks per half (n = 2^19)
    const int l = 2 * p + h;
    const int c = (b & 16383) >> 3;
    const int idx = c * 256 + threadIdx.x;
    if (idx >= n || l >= LEVELS) return;

    const float px = pos[3 * idx + 0];
    const float py = pos[3 * idx + 1];
    const float pz = pos[3 * idx + 2];

    const float resf = (float)(16 << l);
    const float tx = px * resf, ty = py * resf, tz = pz * resf;
    const float fx = floorf(tx), fy = floorf(ty), fz = floorf(tz);
    const float wx = tx - fx, wy = ty - fy, wz = tz - fz;
    const unsigned ix = (unsigned)(int)fx;
    const unsigned iy = (unsigned)(int)fy;
    const unsigned iz = (unsigned)(int)fz;
    const unsigned hy0 = iy * 2654435761u, hy1 = hy0 + 2654435761u;
    const unsigned hz0 = iz * 805459861u,  hz1 = hz0 + 805459861u;
    const unsigned ix1 = ix + 1u;

    const unsigned int* tb = tb16 + (size_t)l * TBL;
    const unsigned hA = hy0 ^ hz0;        // (y=0,z=0)
    const unsigned hB = hy0 ^ hz1;        // (y=0,z=1)
    const unsigned hC = hy1 ^ hz0;        // (y=1,z=0)
    const unsigned hD = hy1 ^ hz1;        // (y=1,z=1)

    unsigned eA0, eA1, eB0, eB1, eC0, eC1, eD0, eD1;   // e{combo}{x}
    if ((ix & 1u) == 0u) {
        // even ix: {ix^h, (ix+1)^h} = {m, m^1} -> one aligned 8B load
        const uint2 pA = *(const uint2*)&tb[((ix ^ hA) & TMASK) & ~1u];
        const uint2 pB = *(const uint2*)&tb[((ix ^ hB) & TMASK) & ~1u];
        const uint2 pC = *(const uint2*)&tb[((ix ^ hC) & TMASK) & ~1u];
        const uint2 pD = *(const uint2*)&tb[((ix ^ hD) & TMASK) & ~1u];
        const unsigned sA = hA & 1u, sB = hB & 1u, sC = hC & 1u, sD = hD & 1u;
        eA0 = sA ? pA.y : pA.x;  eA1 = sA ? pA.x : pA.y;
        eB0 = sB ? pB.y : pB.x;  eB1 = sB ? pB.x : pB.y;
        eC0 = sC ? pC.y : pC.x;  eC1 = sC ? pC.x : pC.y;
        eD0 = sD ? pD.y : pD.x;  eD1 = sD ? pD.x : pD.y;
    } else {
        eA0 = tb[(ix  ^ hA) & TMASK];  eA1 = tb[(ix1 ^ hA) & TMASK];
        eB0 = tb[(ix  ^ hB) & TMASK];  eB1 = tb[(ix1 ^ hB) & TMASK];
        eC0 = tb[(ix  ^ hC) & TMASK];  eC1 = tb[(ix1 ^ hC) & TMASK];
        eD0 = tb[(ix  ^ hD) & TMASK];  eD1 = tb[(ix1 ^ hD) & TMASK];
    }

#define UNPX(e) __uint_as_float((e) << 16)
#define UNPY(e) __uint_as_float((e) & 0xffff0000u)

    const float ux = 1.f - wx, uy = 1.f - wy, uz = 1.f - wz;
    const float c000 = ux * uy * uz, c001 = ux * uy * wz;
    const float c010 = ux * wy * uz, c011 = ux * wy * wz;
    const float c100 = wx * uy * uz, c101 = wx * uy * wz;
    const float c110 = wx * wy * uz, c111 = wx * wy * wz;

    float f0 = UNPX(eA0) * c000, f1 = UNPY(eA0) * c000;
    f0 = fmaf(UNPX(eB0), c001, f0); f1 = fmaf(UNPY(eB0), c001, f1);
    f0 = fmaf(UNPX(eC0), c010, f0); f1 = fmaf(UNPY(eC0), c010, f1);
    f0 = fmaf(UNPX(eD0), c011, f0); f1 = fmaf(UNPY(eD0), c011, f1);
    f0 = fmaf(UNPX(eA1), c100, f0); f1 = fmaf(UNPY(eA1), c100, f1);
    f0 = fmaf(UNPX(eB1), c101, f0); f1 = fmaf(UNPY(eB1), c101, f1);
    f0 = fmaf(UNPX(eC1), c110, f0); f1 = fmaf(UNPY(eC1), c110, f1);
    f0 = fmaf(UNPX(eD1), c111, f0); f1 = fmaf(UNPY(eD1), c111, f1);

    const unsigned int h0 = f2bf(f0);
    const unsigned int h1 = f2bf(f1);
    __builtin_nontemporal_store((h1 << 16) | h0, &wsp[(size_t)l * n + idx]);
}

// ------------------------------------------------------------------
// Kernel 2: split-precision MFMA MLP, persistent blocks.
// R16: __launch_bounds__(512, 4) (VGPR cap 128) to get 2 blocks/CU
// (LDS 81,152 x2 = 162.3 KB <= 160 KiB) -> 16 waves/CU, 2x latency
// hiding on the serial LDS-roundtrip chain. Spill risk from R3 is
// mitigated: SPLIT_TILE stages B-tiles (2 live, not 4) and the SH
// section now computes-and-stores each value immediately under its
// qd predicate (peak SH liveness 25 -> ~10 regs; identical exprs,
// bit-identical output). If counters show symmetric FETCH/WRITE
// inflation again, it spilled -> revert to (512,2).
// ------------------------------------------------------------------
#define MT   512
#define GROUPS 8
#define SW1  32                  // Wd1 k-stride (shorts), rows 16B-aligned
#define SW   72                  // 64-k weight stride (shorts), rows 16B-aligned
#define SA   65                  // act k-stride (floats)
#define OW1  0                   // 64*32 = 2048
#define OW2  2048                // 16*72 = 1152
#define OC1H 3200                // 64*72 = 4608
#define OC1L 7808
#define OC2H 12416
#define OC2L 17024
#define OC3H 21632               // 16*72 = 1152
#define OC3L 22784
#define WTOT 23936               // shorts = 47,872 B; + act 33,280 B = 81,152 B

__global__ __launch_bounds__(512, 4)
void ngp_mlp_mfma4(const unsigned int* __restrict__ wsp,
                   const float* __restrict__ dirp,
                   const float* __restrict__ Wd1, const float* __restrict__ bd1,
                   const float* __restrict__ Wd2, const float* __restrict__ bd2,
                   const float* __restrict__ Wc1, const float* __restrict__ bc1,
                   const float* __restrict__ Wc2, const float* __restrict__ bc2,
                   const float* __restrict__ Wc3, const float* __restrict__ bc3,
                   float* __restrict__ out, int n)
{
    __shared__ short wsm[WTOT];
    __shared__ float act[8 * 16 * SA];
    const int tid = threadIdx.x;

    for (int t = tid; t < WTOT; t += MT) wsm[t] = 0;
    __syncthreads();

    for (int g = tid; g < 32 * 64; g += MT) {            // Wd1 (32,64) single
        const int k = g >> 6, nn = g & 63;
        wsm[OW1 + nn * SW1 + k] = f2bf(Wd1[g]);
    }
    for (int g = tid; g < 64 * 16; g += MT) {            // Wd2 (64,16) single
        const int k = g >> 4, nn = g & 15;
        wsm[OW2 + nn * SW + k] = f2bf(Wd2[g]);
    }
    for (int g = tid; g < 41 * 64; g += MT) {            // Wc1 (41,64) hi+lo
        const int k = g >> 6, nn = g & 63;
        const float w = Wc1[g];
        const unsigned short hh = f2bf(w);
        wsm[OC1H + nn * SW + k] = hh;
        wsm[OC1L + nn * SW + k] = f2bf(w - b2f(hh));
    }
    for (int g = tid; g < 64 * 64; g += MT) {            // Wc2 (64,64) hi+lo
        const int k = g >> 6, nn = g & 63;
        const float w = Wc2[g];
        const unsigned short hh = f2bf(w);
        wsm[OC2H + nn * SW + k] = hh;
        wsm[OC2L + nn * SW + k] = f2bf(w - b2f(hh));
    }
    for (int g = tid; g < 64 * 3; g += MT) {             // Wc3 (64,3) hi+lo
        const int k = g / 3, nn = g - 3 * k;
        const float w = Wc3[g];
        const unsigned short hh = f2bf(w);
        wsm[OC3H + nn * SW + k] = hh;
        wsm[OC3L + nn * SW + k] = f2bf(w - b2f(hh));
    }
    __syncthreads();

    const int wid = tid >> 6;              // 0..7
    const int lane = tid & 63;
    const int ln = lane & 15;
    const int qd = lane >> 4;
    float* A = act + wid * (16 * SA);

    // biases hoisted to registers (loop-invariant)
    float bd1v[4], bc1v[4], bc2v[4];
#pragma unroll
    for (int t = 0; t < 4; ++t) {
        bd1v[t] = bd1[t * 16 + ln];
        bc1v[t] = bc1[t * 16 + ln];
        bc2v[t] = bc2[t * 16 + ln];
    }
    const float bd2v = bd2[ln];
    const float bc3v = (ln < 3) ? bc3[ln] : 0.f;

#define LOAD_SPLIT(ah, al, k0)                                   \
    {                                                            \
        _Pragma("unroll")                                        \
        for (int j = 0; j < 8; ++j) {                            \
            const float v = A[ln * SA + (k0) + j];               \
            const unsigned short hb = f2bf(v);                   \
            ah[j] = (short)hb;                                   \
            al[j] = (short)f2bf(v - b2f(hb));                    \
        }                                                        \
    }

// hi-half B-tiles first, 4 MFMAs, then lo-half B-tiles, 2 MFMAs:
// same accumulation order as before (bit-identical), but only 2
// B-tiles (8 VGPR) live at any point instead of 4 (16).
#define SPLIT_TILE(acc, ah0, ah1, al0, al1, OH, OL, row)                                          \
    {                                                                                             \
        const bf16x8 bh0 = *(const bf16x8*)&wsm[(OH) + (row) * SW + qd * 8];                      \
        const bf16x8 bh1 = *(const bf16x8*)&wsm[(OH) + (row) * SW + 32 + qd * 8];                 \
        acc = __builtin_amdgcn_mfma_f32_16x16x32_bf16(ah0, bh0, acc, 0, 0, 0);                    \
        acc = __builtin_amdgcn_mfma_f32_16x16x32_bf16(ah1, bh1, acc, 0, 0, 0);                    \
        acc = __builtin_amdgcn_mfma_f32_16x16x32_bf16(al0, bh0, acc, 0, 0, 0);                    \
        acc = __builtin_amdgcn_mfma_f32_16x16x32_bf16(al1, bh1, acc, 0, 0, 0);                    \
        const bf16x8 bl0 = *(const bf16x8*)&wsm[(OL) + (row) * SW + qd * 8];                      \
        const bf16x8 bl1 = *(const bf16x8*)&wsm[(OL) + (row) * SW + 32 + qd * 8];                 \
        acc = __builtin_amdgcn_mfma_f32_16x16x32_bf16(ah0, bl0, acc, 0, 0, 0);                    \
        acc = __builtin_amdgcn_mfma_f32_16x16x32_bf16(ah1, bl1, acc, 0, 0, 0);                    \
    }

    // ---- register prefetch of group 0's globals (packed bf16 planes) ----
    const int pt0 = blockIdx.x * (GROUPS * 128) + wid * 16 + ln;
    unsigned int xu0, xu1, xu2, xu3;
    float dq0, dq1, dq2;
    xu0 = wsp[(size_t)(qd * 4 + 0) * n + pt0];
    xu1 = wsp[(size_t)(qd * 4 + 1) * n + pt0];
    xu2 = wsp[(size_t)(qd * 4 + 2) * n + pt0];
    xu3 = wsp[(size_t)(qd * 4 + 3) * n + pt0];
    dq0 = dirp[3 * pt0 + 0];
    dq1 = dirp[3 * pt0 + 1];
    dq2 = dirp[3 * pt0 + 2];

#pragma unroll 1
    for (int grp = 0; grp < GROUPS; ++grp) {
        const int pt_base = blockIdx.x * (GROUPS * 128) + grp * 128 + wid * 16;
        const int pt = pt_base + ln;

        // consume prefetched globals (already bf16 bits — no converts)
        bf16x8 ax;
        ax[0] = (short)(xu0 & 0xffffu); ax[1] = (short)(xu0 >> 16);
        ax[2] = (short)(xu1 & 0xffffu); ax[3] = (short)(xu1 >> 16);
        ax[4] = (short)(xu2 & 0xffffu); ax[5] = (short)(xu2 >> 16);
        ax[6] = (short)(xu3 & 0xffffu); ax[7] = (short)(xu3 >> 16);
        const float ddx = dq0, ddy = dq1, ddz = dq2;

        // issue next group's globals now (consumed next iteration)
        if (grp + 1 < GROUPS) {
            const int ptn = pt + 128;
            xu0 = wsp[(size_t)(qd * 4 + 0) * n + ptn];
            xu1 = wsp[(size_t)(qd * 4 + 1) * n + ptn];
            xu2 = wsp[(size_t)(qd * 4 + 2) * n + ptn];
            xu3 = wsp[(size_t)(qd * 4 + 3) * n + ptn];
            dq0 = dirp[3 * ptn + 0];
            dq1 = dirp[3 * ptn + 1];
            dq2 = dirp[3 * ptn + 2];
        }

        // ---- d1: Y[16x64] = X @ Wd1 (single bf16) ----
        f32x4 yacc[4];
#pragma unroll
        for (int t = 0; t < 4; ++t) {
            const bf16x8 b = *(const bf16x8*)&wsm[OW1 + (t * 16 + ln) * SW1 + qd * 8];
            const float bv = bd1v[t];
            f32x4 acc = {bv, bv, bv, bv};
            yacc[t] = __builtin_amdgcn_mfma_f32_16x16x32_bf16(ax, b, acc, 0, 0, 0);
        }
#pragma unroll
        for (int t = 0; t < 4; ++t)
#pragma unroll
            for (int r = 0; r < 4; ++r)
                A[(qd * 4 + r) * SA + t * 16 + ln] = fmaxf(yacc[t][r], 0.f);   // fp32

        // ---- d2: D[16x16] = relu(Y) @ Wd2 (single bf16) ----
        {
            bf16x8 a0, a1;
#pragma unroll
            for (int j = 0; j < 8; ++j) a0[j] = (short)f2bf(A[ln * SA + qd * 8 + j]);
#pragma unroll
            for (int j = 0; j < 8; ++j) a1[j] = (short)f2bf(A[ln * SA + 32 + qd * 8 + j]);
            const bf16x8 b0 = *(const bf16x8*)&wsm[OW2 + ln * SW + qd * 8];
            const bf16x8 b1 = *(const bf16x8*)&wsm[OW2 + ln * SW + 32 + qd * 8];
            const float bv = bd2v;
            f32x4 acc = {bv, bv, bv, bv};
            acc = __builtin_amdgcn_mfma_f32_16x16x32_bf16(a0, b0, acc, 0, 0, 0);
            acc = __builtin_amdgcn_mfma_f32_16x16x32_bf16(a1, b1, acc, 0, 0, 0);
            if (ln == 15) {
#pragma unroll
                for (int r = 0; r < 4; ++r)
                    out[3 * n + pt_base + qd * 4 + r] = fmaxf(acc[r], 0.f);    // sigma
            }
#pragma unroll
            for (int r = 0; r < 4; ++r)
                A[(qd * 4 + r) * SA + ln] = acc[r];        // raw D fp32, k=0..15
        }

        // ---- SH -> act fp32, k=16..40 (k=41..63 stale, Wc1 rows zeroed) ----
        // R16: compute-and-store each value immediately under its qd
        // predicate: same expressions (bit-identical), peak liveness
        // 25 regs -> ~10 (shared subexpressions only).
        {
            const float dxv = ddx, dyv = ddy, dzv = ddz;
            const float x2 = dxv * dxv, y2 = dyv * dyv, z2 = dzv * dzv;
            const float xy = dxv * dyv, xz = dxv * dzv, yz = dyv * dzv;
            const float x4 = x2 * x2, y4 = y2 * y2;
            const float c0  = (float)(0.5 * sqrt(1.0 / M_PI));
            const float c1  = (float)(0.5 * sqrt(3.0 / M_PI));
            const float sub = (float)(0.25 * sqrt(5.0 / M_PI));
            const float v1  = (float)(0.25 * sqrt(15.0 / M_PI));
            const float v2  = (float)(0.5 * sqrt(15.0 / M_PI));
            const float v3  = (float)(0.75 * sqrt(5.0 / M_PI));
            const float w1c = (float)(0.25 * sqrt(105.0 / M_PI));
            const float w2c = (float)(0.5 * sqrt(105.0 / M_PI));
            const float w3c = (float)(0.25 * sqrt(35.0 / (2.0 * M_PI)));
            const float w4c = (float)(0.5 * sqrt(7.0 / (6.0 * M_PI)));
            float* Ash = &A[ln * SA + 16];
#define SH_PUT(i, expr) { if (((i) & 3) == qd) Ash[i] = (expr); }
            SH_PUT(0,  c0)
            SH_PUT(1,  -c1 * dyv)
            SH_PUT(2,   c1 * dzv)
            SH_PUT(3,  -c1 * dxv)
            SH_PUT(4,   v2 * xy)
            SH_PUT(5,  -v2 * yz)
            SH_PUT(6,   v3 * z2 - sub)
            SH_PUT(7,  -v2 * xz)
            SH_PUT(8,   v1 * x2 - v1 * y2)
            SH_PUT(9,  -w3c * dyv * (3.0f * x2 - y2))
            SH_PUT(10,  w2c * xy * dzv)
            SH_PUT(11,  w4c * dyv * (1.5f - 7.5f * z2))
            SH_PUT(12,  1.24392110863372f * dzv * (1.5f * z2 - 0.5f) - 0.497568443453487f * dzv)
            SH_PUT(13,  w4c * dxv * (1.5f - 7.5f * z2))
            SH_PUT(14,  w1c * dzv * (x2 - y2))
            SH_PUT(15, -w3c * dxv * (x2 - 3.0f * y2))
            SH_PUT(16,  2.5033429417967f * xy * (x2 - y2))
            SH_PUT(17, -1.77013076977993f * yz * (3.0f * x2 - y2))
            SH_PUT(18,  0.126156626101008f * xy * (52.5f * z2 - 7.5f))
            SH_PUT(19,  0.267618617422916f * dyv * (2.33333333333333f * dzv * (1.5f - 7.5f * z2) + 4.0f * dzv))
            SH_PUT(20,  1.48099765681286f * dzv * (1.66666666666667f * dzv * (1.5f * z2 - 0.5f) - 0.666666666666667f * dzv)
                        - 0.952069922236839f * z2 + 0.317356640745613f)
            SH_PUT(21,  0.267618617422916f * dxv * (2.33333333333333f * dzv * (1.5f - 7.5f * z2) + 4.0f * dzv))
            SH_PUT(22,  0.063078313050504f * (x2 - y2) * (52.5f * z2 - 7.5f))
            SH_PUT(23, -1.77013076977993f * xz * (x2 - 3.0f * y2))
            SH_PUT(24, -3.75501441269506f * x2 * y2 + 0.625835735449176f * x4 + 0.625835735449176f * y4)
#undef SH_PUT
        }

        // ---- c1: H1 = [D|SH|0] @ Wc1 (split) ----
        {
            bf16x8 ah0, ah1, al0, al1;
            LOAD_SPLIT(ah0, al0, qd * 8)
            LOAD_SPLIT(ah1, al1, 32 + qd * 8)
            f32x4 hacc[4];
#pragma unroll
            for (int t = 0; t < 4; ++t) {
                const float bv = bc1v[t];
                f32x4 acc = {bv, bv, bv, bv};
                SPLIT_TILE(acc, ah0, ah1, al0, al1, OC1H, OC1L, t * 16 + ln)
                hacc[t] = acc;
            }
#pragma unroll
            for (int t = 0; t < 4; ++t)
#pragma unroll
                for (int r = 0; r < 4; ++r)
                    A[(qd * 4 + r) * SA + t * 16 + ln] = fmaxf(hacc[t][r], 0.f);
        }

        // ---- c2: H2 = relu(H1) @ Wc2 (split) ----
        {
            bf16x8 ah0, ah1, al0, al1;
            LOAD_SPLIT(ah0, al0, qd * 8)
            LOAD_SPLIT(ah1, al1, 32 + qd * 8)
            f32x4 hacc[4];
#pragma unroll
            for (int t = 0; t < 4; ++t) {
                const float bv = bc2v[t];
                f32x4 acc = {bv, bv, bv, bv};
                SPLIT_TILE(acc, ah0, ah1, al0, al1, OC2H, OC2L, t * 16 + ln)
                hacc[t] = acc;
            }
#pragma unroll
            for (int t = 0; t < 4; ++t)
#pragma unroll
                for (int r = 0; r < 4; ++r)
                    A[(qd * 4 + r) * SA + t * 16 + ln] = fmaxf(hacc[t][r], 0.f);
        }

        // ---- c3 + sigmoid: R = relu(H2) @ Wc3 (split) ----
        {
            bf16x8 ah0, ah1, al0, al1;
            LOAD_SPLIT(ah0, al0, qd * 8)
            LOAD_SPLIT(ah1, al1, 32 + qd * 8)
            const float bv = bc3v;
            f32x4 acc = {bv, bv, bv, bv};
            SPLIT_TILE(acc, ah0, ah1, al0, al1, OC3H, OC3L, ln)
            if (ln < 3) {
#pragma unroll
                for (int r = 0; r < 4; ++r)
                    out[3 * (pt_base + qd * 4 + r) + ln] = 1.f / (1.f + expf(-acc[r]));
            }
        }
    }
}

// ------------------------------------------------------------------
// Fallback: round-1 fused kernel (if ws too small / n not 2^19) — proven
// ------------------------------------------------------------------
__global__ __launch_bounds__(256)
void nerf_fused(const float* __restrict__ pos,
                const float* __restrict__ dirp,
                const float* __restrict__ tables,
                const float* __restrict__ Wd1, const float* __restrict__ bd1,
                const float* __restrict__ Wd2, const float* __restrict__ bd2,
                const float* __restrict__ Wc1, const float* __restrict__ bc1,
                const float* __restrict__ Wc2, const float* __restrict__ bc2,
                const float* __restrict__ Wc3, const float* __restrict__ bc3,
                float* __restrict__ out, int n)
{
    const int idx = blockIdx.x * blockDim.x + threadIdx.x;
    if (idx >= n) return;
    const float px = pos[3 * idx + 0], py = pos[3 * idx + 1], pz = pos[3 * idx + 2];
    float y[64];
#pragma unroll
    for (int j = 0; j < 64; ++j) y[j] = bd1[j];
#pragma unroll
    for (int l = 0; l < LEVELS; ++l) {
        const float resf = (float)(16 << l);
        const float tx = px * resf, ty = py * resf, tz = pz * resf;
        const float fx = floorf(tx), fy = floorf(ty), fz = floorf(tz);
        const float wx = tx - fx, wy = ty - fy, wz = tz - fz;
        const unsigned ix = (unsigned)(int)fx, iy = (unsigned)(int)fy, iz = (unsigned)(int)fz;
        const unsigned hy0 = iy * 2654435761u, hy1 = hy0 + 2654435761u;
        const unsigned hz0 = iz * 805459861u,  hz1 = hz0 + 805459861u;
        const unsigned ix1 = ix + 1u;
        const float2* tb = (const float2*)tables + (size_t)l * TBL;
        const float2 e000 = tb[(ix  ^ hy0 ^ hz0) & TMASK];
        const float2 e001 = tb[(ix  ^ hy0 ^ hz1) & TMASK];
        const float2 e010 = tb[(ix  ^ hy1 ^ hz0) & TMASK];
        const float2 e011 = tb[(ix  ^ hy1 ^ hz1) & TMASK];
        const float2 e100 = tb[(ix1 ^ hy0 ^ hz0) & TMASK];
        const float2 e101 = tb[(ix1 ^ hy0 ^ hz1) & TMASK];
        const float2 e110 = tb[(ix1 ^ hy1 ^ hz0) & TMASK];
        const float2 e111 = tb[(ix1 ^ hy1 ^ hz1) & TMASK];
        const float ux = 1.f - wx, uy = 1.f - wy, uz = 1.f - wz;
        const float c000 = ux*uy*uz, c001 = ux*uy*wz, c010 = ux*wy*uz, c011 = ux*wy*wz;
        const float c100 = wx*uy*uz, c101 = wx*uy*wz, c110 = wx*wy*uz, c111 = wx*wy*wz;
        float f0 = e000.x*c000, f1 = e000.y*c000;
        f0 = fmaf(e001.x,c001,f0); f1 = fmaf(e001.y,c001,f1);
        f0 = fmaf(e010.x,c010,f0); f1 = fmaf(e010.y,c010,f1);
        f0 = fmaf(e011.x,c011,f0); f1 = fmaf(e011.y,c011,f1);
        f0 = fmaf(e100.x,c100,f0); f1 = fmaf(e100.y,c100,f1);
        f0 = fmaf(e101.x,c101,f0); f1 = fmaf(e101.y,c101,f1);
        f0 = fmaf(e110.x,c110,f0); f1 = fmaf(e110.y,c110,f1);
        f0 = fmaf(e111.x,c111,f0); f1 = fmaf(e111.y,c111,f1);
        const float* w0 = Wd1 + (size_t)(2 * l) * 64;
#pragma unroll
        for (int j = 0; j < 64; ++j)
            y[j] = fmaf(f0, w0[j], fmaf(f1, w0[64 + j], y[j]));
    }
    float d[16];
#pragma unroll
    for (int k = 0; k < 16; ++k) d[k] = bd2[k];
#pragma unroll
    for (int j = 0; j < 64; ++j) {
        const float a = fmaxf(y[j], 0.f);
#pragma unroll
        for (int k = 0; k < 16; ++k) d[k] = fmaf(a, Wd2[j * 16 + k], d[k]);
    }
    out[3 * n + idx] = fmaxf(d[15], 0.f);
    const float dx = dirp[3*idx], dy = dirp[3*idx+1], dz = dirp[3*idx+2];
    float sh[25];
    SH_BLOCK(sh, dx, dy, dz)
    float h1[64];
#pragma unroll
    for (int j = 0; j < 64; ++j) h1[j] = bc1[j];
#pragma unroll
    for (int i = 0; i < 16; ++i) {
#pragma unroll
        for (int j = 0; j < 64; ++j) h1[j] = fmaf(d[i], Wc1[i * 64 + j], h1[j]);
    }
#pragma unroll
    for (int s = 0; s < 25; ++s) {
#pragma unroll
        for (int j = 0; j < 64; ++j) h1[j] = fmaf(sh[s], Wc1[(16 + s) * 64 + j], h1[j]);
    }
    float h2[64];
#pragma unroll
    for (int j = 0; j < 64; ++j) h2[j] = bc2[j];
#pragma unroll
    for (int i = 0; i < 64; ++i) {
        const float a = fmaxf(h1[i], 0.f);
#pragma unroll
        for (int j = 0; j < 64; ++j) h2[j] = fmaf(a, Wc2[i * 64 + j], h2[j]);
    }
    float r0 = bc3[0], r1 = bc3[1], r2 = bc3[2];
#pragma unroll
    for (int j = 0; j < 64; ++j) {
        const float a = fmaxf(h2[j], 0.f);
        r0 = fmaf(a, Wc3[j * 3 + 0], r0);
        r1 = fmaf(a, Wc3[j * 3 + 1], r1);
        r2 = fmaf(a, Wc3[j * 3 + 2], r2);
    }
    out[3 * idx + 0] = 1.f / (1.f + expf(-r0));
    out[3 * idx + 1] = 1.f / (1.f + expf(-r1));
    out[3 * idx + 2] = 1.f / (1.f + expf(-r2));
}

extern "C" void kernel_launch(void* const* d_in, const int* in_sizes, int n_in,
                              void* d_out, int out_size, void* d_ws, size_t ws_size,
                              hipStream_t stream) {
    const float* pos    = (const float*)d_in[0];
    const float* dir    = (const float*)d_in[1];
    const float* tables = (const float*)d_in[2];
    const float* Wd1 = (const float*)d_in[3];
    const float* bd1 = (const float*)d_in[4];
    const float* Wd2 = (const float*)d_in[5];
    const float* bd2 = (const float*)d_in[6];
    const float* Wc1 = (const float*)d_in[7];
    const float* bc1 = (const float*)d_in[8];
    const float* Wc2 = (const float*)d_in[9];
    const float* bc2 = (const float*)d_in[10];
    const float* Wc3 = (const float*)d_in[11];
    const float* bc3 = (const float*)d_in[12];

    const int n = in_sizes[0] / 3;
    const int blocks = (n + 255) / 256;

    // workspace layout: [0, n*64) packed-bf16 feature planes;
    //                   [n*64, n*128) packed-bf16 tables (16*TBL uints)
    if (ws_size >= (size_t)n * 128 && n == 524288) {
        unsigned int* wsp  = (unsigned int*)d_ws;
        unsigned int* tb16 = (unsigned int*)((char*)d_ws + (size_t)n * 64);
        const int total = LEVELS * TBL;
        cvt_tables<<<total / 1024, 256, 0, stream>>>(tables, tb16, total);
        ngp_encode_lvl<<<16 * blocks, 256, 0, stream>>>(pos, tb16, wsp, n);
        ngp_mlp_mfma4<<<n / (128 * GROUPS), MT, 0, stream>>>((const unsigned int*)wsp, dir,
                                                             Wd1, bd1, Wd2, bd2,
                                                             Wc1, bc1, Wc2, bc2, Wc3, bc3,
                                                             (float*)d_out, n);
    } else {
        nerf_fused<<<blocks, 256, 0, stream>>>(pos, dir, tables,
                                               Wd1, bd1, Wd2, bd2,
                                               Wc1, bc1, Wc2, bc2, Wc3, bc3,
                                               (float*)d_out, n);
    }
}

// Round 7
// 355.303 us; speedup vs baseline: 1.4001x; 1.0108x over previous
//
#include <hip/hip_runtime.h>
#include <math.h>

#define LEVELS 16
#define TBL 524288          // 2^19 entries per level
#define TMASK (TBL - 1)

typedef short bf16x8 __attribute__((ext_vector_type(8)));
typedef float f32x4  __attribute__((ext_vector_type(4)));
typedef float fvec4  __attribute__((ext_vector_type(4)));
typedef unsigned int uvec4 __attribute__((ext_vector_type(4)));

static __device__ __forceinline__ unsigned short f2bf(float x) {
    unsigned u = __float_as_uint(x);
    u += 0x7fffu + ((u >> 16) & 1u);    // RNE
    return (unsigned short)(u >> 16);
}
static __device__ __forceinline__ float b2f(unsigned short h) {
    return __uint_as_float(((unsigned)h) << 16);
}

// SH degree-4 block, constants computed exactly as round-1 (verified correct).
#define SH_BLOCK(sh, dx, dy, dz)                                                          \
    const float x2 = dx * dx, y2 = dy * dy, z2 = dz * dz;                                 \
    const float xy = dx * dy, xz = dx * dz, yz = dy * dz;                                 \
    const float x4 = x2 * x2, y4 = y2 * y2;                                               \
    const float c0  = (float)(0.5 * sqrt(1.0 / M_PI));                                    \
    const float c1  = (float)(0.5 * sqrt(3.0 / M_PI));                                    \
    const float sub = (float)(0.25 * sqrt(5.0 / M_PI));                                   \
    const float v1  = (float)(0.25 * sqrt(15.0 / M_PI));                                  \
    const float v2  = (float)(0.5 * sqrt(15.0 / M_PI));                                   \
    const float v3  = (float)(0.75 * sqrt(5.0 / M_PI));                                   \
    const float w1c = (float)(0.25 * sqrt(105.0 / M_PI));                                 \
    const float w2c = (float)(0.5 * sqrt(105.0 / M_PI));                                  \
    const float w3c = (float)(0.25 * sqrt(35.0 / (2.0 * M_PI)));                          \
    const float w4c = (float)(0.5 * sqrt(7.0 / (6.0 * M_PI)));                            \
    sh[0] = c0;                                                                           \
    sh[1] = -c1 * dy;                                                                     \
    sh[2] =  c1 * dz;                                                                     \
    sh[3] = -c1 * dx;                                                                     \
    sh[4] =  v2 * xy;                                                                     \
    sh[5] = -v2 * yz;                                                                     \
    sh[6] =  v3 * z2 - sub;                                                               \
    sh[7] = -v2 * xz;                                                                     \
    sh[8] =  v1 * x2 - v1 * y2;                                                           \
    sh[9]  = -w3c * dy * (3.0f * x2 - y2);                                                \
    sh[10] =  w2c * xy * dz;                                                              \
    sh[11] =  w4c * dy * (1.5f - 7.5f * z2);                                              \
    sh[12] =  1.24392110863372f * dz * (1.5f * z2 - 0.5f) - 0.497568443453487f * dz;      \
    sh[13] =  w4c * dx * (1.5f - 7.5f * z2);                                              \
    sh[14] =  w1c * dz * (x2 - y2);                                                       \
    sh[15] = -w3c * dx * (x2 - 3.0f * y2);                                                \
    sh[16] =  2.5033429417967f * xy * (x2 - y2);                                          \
    sh[17] = -1.77013076977993f * yz * (3.0f * x2 - y2);                                  \
    sh[18] =  0.126156626101008f * xy * (52.5f * z2 - 7.5f);                              \
    sh[19] =  0.267618617422916f * dy * (2.33333333333333f * dz * (1.5f - 7.5f * z2) + 4.0f * dz); \
    sh[20] =  1.48099765681286f * dz * (1.66666666666667f * dz * (1.5f * z2 - 0.5f) - 0.666666666666667f * dz) \
              - 0.952069922236839f * z2 + 0.317356640745613f;                             \
    sh[21] =  0.267618617422916f * dx * (2.33333333333333f * dz * (1.5f - 7.5f * z2) + 4.0f * dz); \
    sh[22] =  0.063078313050504f * (x2 - y2) * (52.5f * z2 - 7.5f);                       \
    sh[23] = -1.77013076977993f * xz * (x2 - 3.0f * y2);                                  \
    sh[24] = -3.75501441269506f * x2 * y2 + 0.625835735449176f * x4 + 0.625835735449176f * y4;

// ------------------------------------------------------------------
// Kernel 0: pack fp32 tables -> bf16x2 (one uint per entry).
// ------------------------------------------------------------------
__global__ __launch_bounds__(256)
void cvt_tables(const float* __restrict__ tables,
                unsigned int* __restrict__ tb16, int total)
{
    const int i = (blockIdx.x * 256 + threadIdx.x) * 4;   // 4 entries/thread
    if (i >= total) return;
    const fvec4 a = __builtin_nontemporal_load((const fvec4*)(tables + 2 * (size_t)i));
    const fvec4 b = __builtin_nontemporal_load((const fvec4*)(tables + 2 * (size_t)i) + 1);
    uvec4 o;
    o.x = ((unsigned)f2bf(a.y) << 16) | f2bf(a.x);
    o.y = ((unsigned)f2bf(a.w) << 16) | f2bf(a.z);
    o.z = ((unsigned)f2bf(b.y) << 16) | f2bf(b.x);
    o.w = ((unsigned)f2bf(b.w) << 16) | f2bf(b.z);
    __builtin_nontemporal_store(o, (uvec4*)&tb16[i]);
}

// ------------------------------------------------------------------
// Kernel 1: hash-grid gather, level<->XCD affinity (unchanged: at the
// L2-request wall, ~6 req/pt-level avg, 157 us).
// ------------------------------------------------------------------
__global__ __launch_bounds__(256)
void ngp_encode_lvl(const float* __restrict__ pos,
                    const unsigned int* __restrict__ tb16,
                    unsigned int* __restrict__ wsp, int n)
{
    const int b = blockIdx.x;
    const int p = b & 7;
    const int h = b >> 14;                 // 16384 blocks per half (n = 2^19)
    const int l = 2 * p + h;
    const int c = (b & 16383) >> 3;
    const int idx = c * 256 + threadIdx.x;
    if (idx >= n || l >= LEVELS) return;

    const float px = pos[3 * idx + 0];
    const float py = pos[3 * idx + 1];
    const float pz = pos[3 * idx + 2];

    const float resf = (float)(16 << l);
    const float tx = px * resf, ty = py * resf, tz = pz * resf;
    const float fx = floorf(tx), fy = floorf(ty), fz = floorf(tz);
    const float wx = tx - fx, wy = ty - fy, wz = tz - fz;
    const unsigned ix = (unsigned)(int)fx;
    const unsigned iy = (unsigned)(int)fy;
    const unsigned iz = (unsigned)(int)fz;
    const unsigned hy0 = iy * 2654435761u, hy1 = hy0 + 2654435761u;
    const unsigned hz0 = iz * 805459861u,  hz1 = hz0 + 805459861u;
    const unsigned ix1 = ix + 1u;

    const unsigned int* tb = tb16 + (size_t)l * TBL;
    const unsigned hA = hy0 ^ hz0;        // (y=0,z=0)
    const unsigned hB = hy0 ^ hz1;        // (y=0,z=1)
    const unsigned hC = hy1 ^ hz0;        // (y=1,z=0)
    const unsigned hD = hy1 ^ hz1;        // (y=1,z=1)

    unsigned eA0, eA1, eB0, eB1, eC0, eC1, eD0, eD1;   // e{combo}{x}
    if ((ix & 1u) == 0u) {
        // even ix: {ix^h, (ix+1)^h} = {m, m^1} -> one aligned 8B load
        const uint2 pA = *(const uint2*)&tb[((ix ^ hA) & TMASK) & ~1u];
        const uint2 pB = *(const uint2*)&tb[((ix ^ hB) & TMASK) & ~1u];
        const uint2 pC = *(const uint2*)&tb[((ix ^ hC) & TMASK) & ~1u];
        const uint2 pD = *(const uint2*)&tb[((ix ^ hD) & TMASK) & ~1u];
        const unsigned sA = hA & 1u, sB = hB & 1u, sC = hC & 1u, sD = hD & 1u;
        eA0 = sA ? pA.y : pA.x;  eA1 = sA ? pA.x : pA.y;
        eB0 = sB ? pB.y : pB.x;  eB1 = sB ? pB.x : pB.y;
        eC0 = sC ? pC.y : pC.x;  eC1 = sC ? pC.x : pC.y;
        eD0 = sD ? pD.y : pD.x;  eD1 = sD ? pD.x : pD.y;
    } else {
        eA0 = tb[(ix  ^ hA) & TMASK];  eA1 = tb[(ix1 ^ hA) & TMASK];
        eB0 = tb[(ix  ^ hB) & TMASK];  eB1 = tb[(ix1 ^ hB) & TMASK];
        eC0 = tb[(ix  ^ hC) & TMASK];  eC1 = tb[(ix1 ^ hC) & TMASK];
        eD0 = tb[(ix  ^ hD) & TMASK];  eD1 = tb[(ix1 ^ hD) & TMASK];
    }

#define UNPX(e) __uint_as_float((e) << 16)
#define UNPY(e) __uint_as_float((e) & 0xffff0000u)

    const float ux = 1.f - wx, uy = 1.f - wy, uz = 1.f - wz;
    const float c000 = ux * uy * uz, c001 = ux * uy * wz;
    const float c010 = ux * wy * uz, c011 = ux * wy * wz;
    const float c100 = wx * uy * uz, c101 = wx * uy * wz;
    const float c110 = wx * wy * uz, c111 = wx * wy * wz;

    float f0 = UNPX(eA0) * c000, f1 = UNPY(eA0) * c000;
    f0 = fmaf(UNPX(eB0), c001, f0); f1 = fmaf(UNPY(eB0), c001, f1);
    f0 = fmaf(UNPX(eC0), c010, f0); f1 = fmaf(UNPY(eC0), c010, f1);
    f0 = fmaf(UNPX(eD0), c011, f0); f1 = fmaf(UNPY(eD0), c011, f1);
    f0 = fmaf(UNPX(eA1), c100, f0); f1 = fmaf(UNPY(eA1), c100, f1);
    f0 = fmaf(UNPX(eB1), c101, f0); f1 = fmaf(UNPY(eB1), c101, f1);
    f0 = fmaf(UNPX(eC1), c110, f0); f1 = fmaf(UNPY(eC1), c110, f1);
    f0 = fmaf(UNPX(eD1), c111, f0); f1 = fmaf(UNPY(eD1), c111, f1);

    const unsigned int h0 = f2bf(f0);
    const unsigned int h1 = f2bf(f1);
    __builtin_nontemporal_store((h1 << 16) | h0, &wsp[(size_t)l * n + idx]);
}

// ------------------------------------------------------------------
// Kernel 2: split-precision MFMA MLP, persistent blocks.
// R17: (a) SA 65->68 (272 B rows, 16 B-aligned) so act reads compile
// to ds_read_b128 (was 16x scalar ds_read_b32 per LOAD_SPLIT);
// (b) Wc3 LDS region 16 -> 4 rows (c3 reads row ln&3; rows>=3 zero,
// ln>=3 results discarded) -> LDS 79,232 B -> 2 blocks/CU under
// (512,4); (c) hacc buffer dropped (A-frags already in regs; direct
// stores are safe & bit-identical; -16 VGPR) and sched_barrier(0)
// between c1/c2 t-iterations so the scheduler cannot hoist all 16
// B-tile b128 loads (the 64-VGPR hoist is what spilled R3/R6).
// ------------------------------------------------------------------
#define MT   512
#define GROUPS 8
#define SW1  32                  // Wd1 k-stride (shorts), rows 16B-aligned
#define SW   72                  // 64-k weight stride (shorts), rows 16B-aligned
#define SA   68                  // act k-stride (floats); 272B rows, 16B-aligned
#define OW1  0                   // 64*32 = 2048
#define OW2  2048                // 16*72 = 1152
#define OC1H 3200                // 64*72 = 4608
#define OC1L 7808
#define OC2H 12416
#define OC2L 17024
#define OC3H 21632               // 4*72 = 288 (rows 0-2 real, row 3 zero)
#define OC3L 21920
#define WTOT 22208               // shorts = 44,416 B; + act 34,816 B = 79,232 B

__global__ __launch_bounds__(512, 4)
void ngp_mlp_mfma4(const unsigned int* __restrict__ wsp,
                   const float* __restrict__ dirp,
                   const float* __restrict__ Wd1, const float* __restrict__ bd1,
                   const float* __restrict__ Wd2, const float* __restrict__ bd2,
                   const float* __restrict__ Wc1, const float* __restrict__ bc1,
                   const float* __restrict__ Wc2, const float* __restrict__ bc2,
                   const float* __restrict__ Wc3, const float* __restrict__ bc3,
                   float* __restrict__ out, int n)
{
    __shared__ short wsm[WTOT];
    __shared__ float act[8 * 16 * SA];
    const int tid = threadIdx.x;

    for (int t = tid; t < WTOT; t += MT) wsm[t] = 0;
    __syncthreads();

    for (int g = tid; g < 32 * 64; g += MT) {            // Wd1 (32,64) single
        const int k = g >> 6, nn = g & 63;
        wsm[OW1 + nn * SW1 + k] = f2bf(Wd1[g]);
    }
    for (int g = tid; g < 64 * 16; g += MT) {            // Wd2 (64,16) single
        const int k = g >> 4, nn = g & 15;
        wsm[OW2 + nn * SW + k] = f2bf(Wd2[g]);
    }
    for (int g = tid; g < 41 * 64; g += MT) {            // Wc1 (41,64) hi+lo
        const int k = g >> 6, nn = g & 63;
        const float w = Wc1[g];
        const unsigned short hh = f2bf(w);
        wsm[OC1H + nn * SW + k] = hh;
        wsm[OC1L + nn * SW + k] = f2bf(w - b2f(hh));
    }
    for (int g = tid; g < 64 * 64; g += MT) {            // Wc2 (64,64) hi+lo
        const int k = g >> 6, nn = g & 63;
        const float w = Wc2[g];
        const unsigned short hh = f2bf(w);
        wsm[OC2H + nn * SW + k] = hh;
        wsm[OC2L + nn * SW + k] = f2bf(w - b2f(hh));
    }
    for (int g = tid; g < 64 * 3; g += MT) {             // Wc3 (64,3) hi+lo
        const int k = g / 3, nn = g - 3 * k;
        const float w = Wc3[g];
        const unsigned short hh = f2bf(w);
        wsm[OC3H + nn * SW + k] = hh;
        wsm[OC3L + nn * SW + k] = f2bf(w - b2f(hh));
    }
    __syncthreads();

    const int wid = tid >> 6;              // 0..7
    const int lane = tid & 63;
    const int ln = lane & 15;
    const int qd = lane >> 4;
    float* A = act + wid * (16 * SA);

    // biases hoisted to registers (loop-invariant)
    float bd1v[4], bc1v[4], bc2v[4];
#pragma unroll
    for (int t = 0; t < 4; ++t) {
        bd1v[t] = bd1[t * 16 + ln];
        bc1v[t] = bc1[t * 16 + ln];
        bc2v[t] = bc2[t * 16 + ln];
    }
    const float bd2v = bd2[ln];
    const float bc3v = (ln < 3) ? bc3[ln] : 0.f;

#define LOAD_SPLIT(ah, al, k0)                                   \
    {                                                            \
        _Pragma("unroll")                                        \
        for (int j = 0; j < 8; ++j) {                            \
            const float v = A[ln * SA + (k0) + j];               \
            const unsigned short hb = f2bf(v);                   \
            ah[j] = (short)hb;                                   \
            al[j] = (short)f2bf(v - b2f(hb));                    \
        }                                                        \
    }

// hi-half B-tiles first, 4 MFMAs, then lo-half B-tiles, 2 MFMAs:
// same accumulation order (bit-identical); 2 B-tiles live at a time.
#define SPLIT_TILE(acc, ah0, ah1, al0, al1, OH, OL, row)                                          \
    {                                                                                             \
        const bf16x8 bh0 = *(const bf16x8*)&wsm[(OH) + (row) * SW + qd * 8];                      \
        const bf16x8 bh1 = *(const bf16x8*)&wsm[(OH) + (row) * SW + 32 + qd * 8];                 \
        acc = __builtin_amdgcn_mfma_f32_16x16x32_bf16(ah0, bh0, acc, 0, 0, 0);                    \
        acc = __builtin_amdgcn_mfma_f32_16x16x32_bf16(ah1, bh1, acc, 0, 0, 0);                    \
        acc = __builtin_amdgcn_mfma_f32_16x16x32_bf16(al0, bh0, acc, 0, 0, 0);                    \
        acc = __builtin_amdgcn_mfma_f32_16x16x32_bf16(al1, bh1, acc, 0, 0, 0);                    \
        const bf16x8 bl0 = *(const bf16x8*)&wsm[(OL) + (row) * SW + qd * 8];                      \
        const bf16x8 bl1 = *(const bf16x8*)&wsm[(OL) + (row) * SW + 32 + qd * 8];                 \
        acc = __builtin_amdgcn_mfma_f32_16x16x32_bf16(ah0, bl0, acc, 0, 0, 0);                    \
        acc = __builtin_amdgcn_mfma_f32_16x16x32_bf16(ah1, bl1, acc, 0, 0, 0);                    \
    }

    // ---- register prefetch of group 0's globals (packed bf16 planes) ----
    const int pt0 = blockIdx.x * (GROUPS * 128) + wid * 16 + ln;
    unsigned int xu0, xu1, xu2, xu3;
    float dq0, dq1, dq2;
    xu0 = wsp[(size_t)(qd * 4 + 0) * n + pt0];
    xu1 = wsp[(size_t)(qd * 4 + 1) * n + pt0];
    xu2 = wsp[(size_t)(qd * 4 + 2) * n + pt0];
    xu3 = wsp[(size_t)(qd * 4 + 3) * n + pt0];
    dq0 = dirp[3 * pt0 + 0];
    dq1 = dirp[3 * pt0 + 1];
    dq2 = dirp[3 * pt0 + 2];

#pragma unroll 1
    for (int grp = 0; grp < GROUPS; ++grp) {
        const int pt_base = blockIdx.x * (GROUPS * 128) + grp * 128 + wid * 16;
        const int pt = pt_base + ln;

        // consume prefetched globals (already bf16 bits — no converts)
        bf16x8 ax;
        ax[0] = (short)(xu0 & 0xffffu); ax[1] = (short)(xu0 >> 16);
        ax[2] = (short)(xu1 & 0xffffu); ax[3] = (short)(xu1 >> 16);
        ax[4] = (short)(xu2 & 0xffffu); ax[5] = (short)(xu2 >> 16);
        ax[6] = (short)(xu3 & 0xffffu); ax[7] = (short)(xu3 >> 16);
        const float ddx = dq0, ddy = dq1, ddz = dq2;

        // issue next group's globals now (consumed next iteration)
        if (grp + 1 < GROUPS) {
            const int ptn = pt + 128;
            xu0 = wsp[(size_t)(qd * 4 + 0) * n + ptn];
            xu1 = wsp[(size_t)(qd * 4 + 1) * n + ptn];
            xu2 = wsp[(size_t)(qd * 4 + 2) * n + ptn];
            xu3 = wsp[(size_t)(qd * 4 + 3) * n + ptn];
            dq0 = dirp[3 * ptn + 0];
            dq1 = dirp[3 * ptn + 1];
            dq2 = dirp[3 * ptn + 2];
        }

        // ---- d1: Y[16x64] = X @ Wd1 (single bf16) ----
#pragma unroll
        for (int t = 0; t < 4; ++t) {
            const bf16x8 b = *(const bf16x8*)&wsm[OW1 + (t * 16 + ln) * SW1 + qd * 8];
            const float bv = bd1v[t];
            f32x4 acc = {bv, bv, bv, bv};
            acc = __builtin_amdgcn_mfma_f32_16x16x32_bf16(ax, b, acc, 0, 0, 0);
#pragma unroll
            for (int r = 0; r < 4; ++r)
                A[(qd * 4 + r) * SA + t * 16 + ln] = fmaxf(acc[r], 0.f);   // fp32
        }

        // ---- d2: D[16x16] = relu(Y) @ Wd2 (single bf16) ----
        {
            bf16x8 a0, a1;
#pragma unroll
            for (int j = 0; j < 8; ++j) a0[j] = (short)f2bf(A[ln * SA + qd * 8 + j]);
#pragma unroll
            for (int j = 0; j < 8; ++j) a1[j] = (short)f2bf(A[ln * SA + 32 + qd * 8 + j]);
            const bf16x8 b0 = *(const bf16x8*)&wsm[OW2 + ln * SW + qd * 8];
            const bf16x8 b1 = *(const bf16x8*)&wsm[OW2 + ln * SW + 32 + qd * 8];
            const float bv = bd2v;
            f32x4 acc = {bv, bv, bv, bv};
            acc = __builtin_amdgcn_mfma_f32_16x16x32_bf16(a0, b0, acc, 0, 0, 0);
            acc = __builtin_amdgcn_mfma_f32_16x16x32_bf16(a1, b1, acc, 0, 0, 0);
            if (ln == 15) {
#pragma unroll
                for (int r = 0; r < 4; ++r)
                    out[3 * n + pt_base + qd * 4 + r] = fmaxf(acc[r], 0.f);    // sigma
            }
#pragma unroll
            for (int r = 0; r < 4; ++r)
                A[(qd * 4 + r) * SA + ln] = acc[r];        // raw D fp32, k=0..15
        }

        // ---- SH -> act fp32, k=16..40 (k=41..63 stale, Wc1 rows zeroed) ----
        // Compute-and-store under qd predicate (low liveness, bit-identical).
        {
            const float dxv = ddx, dyv = ddy, dzv = ddz;
            const float x2 = dxv * dxv, y2 = dyv * dyv, z2 = dzv * dzv;
            const float xy = dxv * dyv, xz = dxv * dzv, yz = dyv * dzv;
            const float x4 = x2 * x2, y4 = y2 * y2;
            const float c0  = (float)(0.5 * sqrt(1.0 / M_PI));
            const float c1  = (float)(0.5 * sqrt(3.0 / M_PI));
            const float sub = (float)(0.25 * sqrt(5.0 / M_PI));
            const float v1  = (float)(0.25 * sqrt(15.0 / M_PI));
            const float v2  = (float)(0.5 * sqrt(15.0 / M_PI));
            const float v3  = (float)(0.75 * sqrt(5.0 / M_PI));
            const float w1c = (float)(0.25 * sqrt(105.0 / M_PI));
            const float w2c = (float)(0.5 * sqrt(105.0 / M_PI));
            const float w3c = (float)(0.25 * sqrt(35.0 / (2.0 * M_PI)));
            const float w4c = (float)(0.5 * sqrt(7.0 / (6.0 * M_PI)));
            float* Ash = &A[ln * SA + 16];
#define SH_PUT(i, expr) { if (((i) & 3) == qd) Ash[i] = (expr); }
            SH_PUT(0,  c0)
            SH_PUT(1,  -c1 * dyv)
            SH_PUT(2,   c1 * dzv)
            SH_PUT(3,  -c1 * dxv)
            SH_PUT(4,   v2 * xy)
            SH_PUT(5,  -v2 * yz)
            SH_PUT(6,   v3 * z2 - sub)
            SH_PUT(7,  -v2 * xz)
            SH_PUT(8,   v1 * x2 - v1 * y2)
            SH_PUT(9,  -w3c * dyv * (3.0f * x2 - y2))
            SH_PUT(10,  w2c * xy * dzv)
            SH_PUT(11,  w4c * dyv * (1.5f - 7.5f * z2))
            SH_PUT(12,  1.24392110863372f * dzv * (1.5f * z2 - 0.5f) - 0.497568443453487f * dzv)
            SH_PUT(13,  w4c * dxv * (1.5f - 7.5f * z2))
            SH_PUT(14,  w1c * dzv * (x2 - y2))
            SH_PUT(15, -w3c * dxv * (x2 - 3.0f * y2))
            SH_PUT(16,  2.5033429417967f * xy * (x2 - y2))
            SH_PUT(17, -1.77013076977993f * yz * (3.0f * x2 - y2))
            SH_PUT(18,  0.126156626101008f * xy * (52.5f * z2 - 7.5f))
            SH_PUT(19,  0.267618617422916f * dyv * (2.33333333333333f * dzv * (1.5f - 7.5f * z2) + 4.0f * dzv))
            SH_PUT(20,  1.48099765681286f * dzv * (1.66666666666667f * dzv * (1.5f * z2 - 0.5f) - 0.666666666666667f * dzv)
                        - 0.952069922236839f * z2 + 0.317356640745613f)
            SH_PUT(21,  0.267618617422916f * dxv * (2.33333333333333f * dzv * (1.5f - 7.5f * z2) + 4.0f * dzv))
            SH_PUT(22,  0.063078313050504f * (x2 - y2) * (52.5f * z2 - 7.5f))
            SH_PUT(23, -1.77013076977993f * xz * (x2 - 3.0f * y2))
            SH_PUT(24, -3.75501441269506f * x2 * y2 + 0.625835735449176f * x4 + 0.625835735449176f * y4)
#undef SH_PUT
        }

        // ---- c1: H1 = [D|SH|0] @ Wc1 (split) ----
        // A-frags are fully in registers before the t-loop, so each t's
        // output store is safe immediately (no hacc buffer needed).
        // sched_barrier(0) between iterations stops the scheduler from
        // hoisting all 16 B-tile b128 loads (the VGPR-spill cause).
        {
            bf16x8 ah0, ah1, al0, al1;
            LOAD_SPLIT(ah0, al0, qd * 8)
            LOAD_SPLIT(ah1, al1, 32 + qd * 8)
#pragma unroll
            for (int t = 0; t < 4; ++t) {
                const float bv = bc1v[t];
                f32x4 acc = {bv, bv, bv, bv};
                SPLIT_TILE(acc, ah0, ah1, al0, al1, OC1H, OC1L, t * 16 + ln)
#pragma unroll
                for (int r = 0; r < 4; ++r)
                    A[(qd * 4 + r) * SA + t * 16 + ln] = fmaxf(acc[r], 0.f);
                __builtin_amdgcn_sched_barrier(0);
            }
        }

        // ---- c2: H2 = relu(H1) @ Wc2 (split) ----
        {
            bf16x8 ah0, ah1, al0, al1;
            LOAD_SPLIT(ah0, al0, qd * 8)
            LOAD_SPLIT(ah1, al1, 32 + qd * 8)
#pragma unroll
            for (int t = 0; t < 4; ++t) {
                const float bv = bc2v[t];
                f32x4 acc = {bv, bv, bv, bv};
                SPLIT_TILE(acc, ah0, ah1, al0, al1, OC2H, OC2L, t * 16 + ln)
#pragma unroll
                for (int r = 0; r < 4; ++r)
                    A[(qd * 4 + r) * SA + t * 16 + ln] = fmaxf(acc[r], 0.f);
                __builtin_amdgcn_sched_barrier(0);
            }
        }

        // ---- c3 + sigmoid: R = relu(H2) @ Wc3 (split) ----
        // B rows 0-2 are real weights, row 3 zeros; ln>=3 discarded.
        {
            bf16x8 ah0, ah1, al0, al1;
            LOAD_SPLIT(ah0, al0, qd * 8)
            LOAD_SPLIT(ah1, al1, 32 + qd * 8)
            const float bv = bc3v;
            f32x4 acc = {bv, bv, bv, bv};
            SPLIT_TILE(acc, ah0, ah1, al0, al1, OC3H, OC3L, (ln & 3))
            if (ln < 3) {
#pragma unroll
                for (int r = 0; r < 4; ++r)
                    out[3 * (pt_base + qd * 4 + r) + ln] = 1.f / (1.f + expf(-acc[r]));
            }
        }
    }
}

// ------------------------------------------------------------------
// Fallback: round-1 fused kernel (if ws too small / n not 2^19) — proven
// ------------------------------------------------------------------
__global__ __launch_bounds__(256)
void nerf_fused(const float* __restrict__ pos,
                const float* __restrict__ dirp,
                const float* __restrict__ tables,
                const float* __restrict__ Wd1, const float* __restrict__ bd1,
                const float* __restrict__ Wd2, const float* __restrict__ bd2,
                const float* __restrict__ Wc1, const float* __restrict__ bc1,
                const float* __restrict__ Wc2, const float* __restrict__ bc2,
                const float* __restrict__ Wc3, const float* __restrict__ bc3,
                float* __restrict__ out, int n)
{
    const int idx = blockIdx.x * blockDim.x + threadIdx.x;
    if (idx >= n) return;
    const float px = pos[3 * idx + 0], py = pos[3 * idx + 1], pz = pos[3 * idx + 2];
    float y[64];
#pragma unroll
    for (int j = 0; j < 64; ++j) y[j] = bd1[j];
#pragma unroll
    for (int l = 0; l < LEVELS; ++l) {
        const float resf = (float)(16 << l);
        const float tx = px * resf, ty = py * resf, tz = pz * resf;
        const float fx = floorf(tx), fy = floorf(ty), fz = floorf(tz);
        const float wx = tx - fx, wy = ty - fy, wz = tz - fz;
        const unsigned ix = (unsigned)(int)fx, iy = (unsigned)(int)fy, iz = (unsigned)(int)fz;
        const unsigned hy0 = iy * 2654435761u, hy1 = hy0 + 2654435761u;
        const unsigned hz0 = iz * 805459861u,  hz1 = hz0 + 805459861u;
        const unsigned ix1 = ix + 1u;
        const float2* tb = (const float2*)tables + (size_t)l * TBL;
        const float2 e000 = tb[(ix  ^ hy0 ^ hz0) & TMASK];
        const float2 e001 = tb[(ix  ^ hy0 ^ hz1) & TMASK];
        const float2 e010 = tb[(ix  ^ hy1 ^ hz0) & TMASK];
        const float2 e011 = tb[(ix  ^ hy1 ^ hz1) & TMASK];
        const float2 e100 = tb[(ix1 ^ hy0 ^ hz0) & TMASK];
        const float2 e101 = tb[(ix1 ^ hy0 ^ hz1) & TMASK];
        const float2 e110 = tb[(ix1 ^ hy1 ^ hz0) & TMASK];
        const float2 e111 = tb[(ix1 ^ hy1 ^ hz1) & TMASK];
        const float ux = 1.f - wx, uy = 1.f - wy, uz = 1.f - wz;
        const float c000 = ux*uy*uz, c001 = ux*uy*wz, c010 = ux*wy*uz, c011 = ux*wy*wz;
        const float c100 = wx*uy*uz, c101 = wx*uy*wz, c110 = wx*wy*uz, c111 = wx*wy*wz;
        float f0 = e000.x*c000, f1 = e000.y*c000;
        f0 = fmaf(e001.x,c001,f0); f1 = fmaf(e001.y,c001,f1);
        f0 = fmaf(e010.x,c010,f0); f1 = fmaf(e010.y,c010,f1);
        f0 = fmaf(e011.x,c011,f0); f1 = fmaf(e011.y,c011,f1);
        f0 = fmaf(e100.x,c100,f0); f1 = fmaf(e100.y,c100,f1);
        f0 = fmaf(e101.x,c101,f0); f1 = fmaf(e101.y,c101,f1);
        f0 = fmaf(e110.x,c110,f0); f1 = fmaf(e110.y,c110,f1);
        f0 = fmaf(e111.x,c111,f0); f1 = fmaf(e111.y,c111,f1);
        const float* w0 = Wd1 + (size_t)(2 * l) * 64;
#pragma unroll
        for (int j = 0; j < 64; ++j)
            y[j] = fmaf(f0, w0[j], fmaf(f1, w0[64 + j], y[j]));
    }
    float d[16];
#pragma unroll
    for (int k = 0; k < 16; ++k) d[k] = bd2[k];
#pragma unroll
    for (int j = 0; j < 64; ++j) {
        const float a = fmaxf(y[j], 0.f);
#pragma unroll
        for (int k = 0; k < 16; ++k) d[k] = fmaf(a, Wd2[j * 16 + k], d[k]);
    }
    out[3 * n + idx] = fmaxf(d[15], 0.f);
    const float dx = dirp[3*idx], dy = dirp[3*idx+1], dz = dirp[3*idx+2];
    float sh[25];
    SH_BLOCK(sh, dx, dy, dz)
    float h1[64];
#pragma unroll
    for (int j = 0; j < 64; ++j) h1[j] = bc1[j];
#pragma unroll
    for (int i = 0; i < 16; ++i) {
#pragma unroll
        for (int j = 0; j < 64; ++j) h1[j] = fmaf(d[i], Wc1[i * 64 + j], h1[j]);
    }
#pragma unroll
    for (int s = 0; s < 25; ++s) {
#pragma unroll
        for (int j = 0; j < 64; ++j) h1[j] = fmaf(sh[s], Wc1[(16 + s) * 64 + j], h1[j]);
    }
    float h2[64];
#pragma unroll
    for (int j = 0; j < 64; ++j) h2[j] = bc2[j];
#pragma unroll
    for (int i = 0; i < 64; ++i) {
        const float a = fmaxf(h1[i], 0.f);
#pragma unroll
        for (int j = 0; j < 64; ++j) h2[j] = fmaf(a, Wc2[i * 64 + j], h2[j]);
    }
    float r0 = bc3[0], r1 = bc3[1], r2 = bc3[2];
#pragma unroll
    for (int j = 0; j < 64; ++j) {
        const float a = fmaxf(h2[j], 0.f);
        r0 = fmaf(a, Wc3[j * 3 + 0], r0);
        r1 = fmaf(a, Wc3[j * 3 + 1], r1);
        r2 = fmaf(a, Wc3[j * 3 + 2], r2);
    }
    out[3 * idx + 0] = 1.f / (1.f + expf(-r0));
    out[3 * idx + 1] = 1.f / (1.f + expf(-r1));
    out[3 * idx + 2] = 1.f / (1.f + expf(-r2));
}

extern "C" void kernel_launch(void* const* d_in, const int* in_sizes, int n_in,
                              void* d_out, int out_size, void* d_ws, size_t ws_size,
                              hipStream_t stream) {
    const float* pos    = (const float*)d_in[0];
    const float* dir    = (const float*)d_in[1];
    const float* tables = (const float*)d_in[2];
    const float* Wd1 = (const float*)d_in[3];
    const float* bd1 = (const float*)d_in[4];
    const float* Wd2 = (const float*)d_in[5];
    const float* bd2 = (const float*)d_in[6];
    const float* Wc1 = (const float*)d_in[7];
    const float* bc1 = (const float*)d_in[8];
    const float* Wc2 = (const float*)d_in[9];
    const float* bc2 = (const float*)d_in[10];
    const float* Wc3 = (const float*)d_in[11];
    const float* bc3 = (const float*)d_in[12];

    const int n = in_sizes[0] / 3;
    const int blocks = (n + 255) / 256;

    // workspace layout: [0, n*64) packed-bf16 feature planes;
    //                   [n*64, n*128) packed-bf16 tables (16*TBL uints)
    if (ws_size >= (size_t)n * 128 && n == 524288) {
        unsigned int* wsp  = (unsigned int*)d_ws;
        unsigned int* tb16 = (unsigned int*)((char*)d_ws + (size_t)n * 64);
        const int total = LEVELS * TBL;
        cvt_tables<<<total / 1024, 256, 0, stream>>>(tables, tb16, total);
        ngp_encode_lvl<<<16 * blocks, 256, 0, stream>>>(pos, tb16, wsp, n);
        ngp_mlp_mfma4<<<n / (128 * GROUPS), MT, 0, stream>>>((const unsigned int*)wsp, dir,
                                                             Wd1, bd1, Wd2, bd2,
                                                             Wc1, bc1, Wc2, bc2, Wc3, bc3,
                                                             (float*)d_out, n);
    } else {
        nerf_fused<<<blocks, 256, 0, stream>>>(pos, dir, tables,
                                               Wd1, bd1, Wd2, bd2,
                                               Wc1, bc1, Wc2, bc2, Wc3, bc3,
                                               (float*)d_out, n);
    }
}